// Round 11
// baseline (45757.309 us; speedup 1.0000x reference)
//
#include <hip/hip_runtime.h>

typedef unsigned short u16;
typedef __attribute__((ext_vector_type(8))) short short8;
typedef __attribute__((ext_vector_type(4))) float f32x4;

__device__ __forceinline__ float bf2f(u16 v){
  union { unsigned u; float f; } t; t.u = ((unsigned)v) << 16; return t.f;
}
__device__ __forceinline__ u16 f2bf(float f){
  union { float f; unsigned u; } t; t.f = f;
  unsigned u = t.u;
  return (u16)((u + 0x7fffu + ((u >> 16) & 1u)) >> 16);
}
struct HiLo { short hi, lo; };
__device__ __forceinline__ HiLo split1(float v){
  HiLo r;
  u16 h = f2bf(v);
  r.hi = (short)h;
  r.lo = (short)f2bf(v - bf2f(h));
  return r;
}
__device__ __forceinline__ void ldw8s(const float* __restrict__ p, short8& hi, short8& lo){
  #pragma unroll
  for (int j = 0; j < 8; ++j){ HiLo s = split1(p[j]); hi[j] = s.hi; lo[j] = s.lo; }
}

#define MFMA(acc, a, b) acc = __builtin_amdgcn_mfma_f32_16x16x32_bf16(a, b, acc, 0,0,0)
#define SMACC(acc, ah, al, bh, bl) do{ MFMA(acc, ah, bh); MFMA(acc, ah, bl); MFMA(acc, al, bh); }while(0)

// ---- prepass: Wcomb = Wih0 @ Wout (2048x512 f32), bb = bih0+bhh0+Wih0@bout -
__global__ void __launch_bounds__(256) wcomb_k(
    const float* __restrict__ Wih0, const float* __restrict__ Wout,
    const float* __restrict__ bout, const float* __restrict__ bih0,
    const float* __restrict__ bhh0,
    float* __restrict__ Wc, float* __restrict__ bb)
{
  __shared__ float wl[8*64];
  __shared__ float bo[64];
  const int wg = blockIdx.x, tid = threadIdx.x;
  const int r0 = wg*8;
  for (int i = tid; i < 512; i += 256) wl[i] = Wih0[(r0 + (i >> 6))*64 + (i & 63)];
  if (tid < 64) bo[tid] = bout[tid];
  __syncthreads();
  if (tid < 8){
    int n = r0 + tid;
    float a = bih0[n] + bhh0[n];
    #pragma unroll 8
    for (int d = 0; d < 64; ++d) a += wl[tid*64 + d]*bo[d];
    bb[n] = a;
  }
  #pragma unroll
  for (int jj = 0; jj < 2; ++jj){
    int j = tid + jj*256;
    float acc[8] = {0,0,0,0,0,0,0,0};
    for (int d = 0; d < 64; ++d){
      float wv = Wout[d*512 + j];
      #pragma unroll
      for (int r = 0; r < 8; ++r) acc[r] += wl[r*64 + d]*wv;
    }
    #pragma unroll
    for (int r = 0; r < 8; ++r) Wc[(r0 + r)*512 + j] = acc[r];
  }
}

// ---- grid barrier (monotone counter, agent-scope acq/rel) ------------------
__device__ __forceinline__ void gbar(unsigned* cnt, unsigned target){
  __syncthreads();
  if (threadIdx.x == 0){
    __threadfence();
    __hip_atomic_fetch_add(cnt, 1u, __ATOMIC_RELEASE, __HIP_MEMORY_SCOPE_AGENT);
    while (__hip_atomic_load(cnt, __ATOMIC_ACQUIRE, __HIP_MEMORY_SCOPE_AGENT) < target)
      __builtin_amdgcn_s_sleep(1);
    __threadfence();
  }
  __syncthreads();
}

// ---- LDS weight-slice helpers (XOR-swizzled, G4) ---------------------------
// slice layout: [16 rows][C cols] bf16, row stride = 2C bytes,
// byte offset ^= (row&7)<<4 kills the stride-2C 16-way bank conflict.
__device__ __forceinline__ short8 lds8(const u16* base, int r, int kelem, int rowbytes){
  int bo = r*rowbytes + (((kelem*2)) ^ ((r & 7) << 4));
  return *(const short8*)((const char*)base + bo);
}
__device__ __forceinline__ void load_slice(
    const float* __restrict__ W, int ldw, int rowshift, int nelem,
    u16* lh, u16* ll, int jq, int tid)
{
  const int rowbytes = ldw*2;
  for (int i = tid; i < nelem; i += 256){
    int r = i >> rowshift, k = i & ((1 << rowshift) - 1);
    int n = ((r >> 2) << 9) + jq*4 + (r & 3);     // gate=(r>>2), col=jq*4+(r&3)
    HiLo s = split1(W[n*ldw + k]);
    int bo = r*rowbytes + (((k*2)) ^ ((r & 7) << 4));
    *(u16*)((char*)lh + bo) = (u16)s.hi;
    *(u16*)((char*)ll + bo) = (u16)s.lo;
  }
}

// ---- persistent kernel: all weights LDS-resident ---------------------------
// WG = (mhalf, jq): 128 batch rows x 4 hidden cols (16 gate rows).
// wave wv: 32 batch rows = 2 M-tiles; MFMA N=16 = 4 gates x 4 cols.
__global__ void __launch_bounds__(256, 1) lstm_persist(
    const float* __restrict__ x,
    const float* __restrict__ Whh0, const float* __restrict__ Wih0,
    const float* __restrict__ Wih1, const float* __restrict__ Whh1,
    const float* __restrict__ Wc,   const float* __restrict__ bb,
    const float* __restrict__ bih0, const float* __restrict__ bhh0,
    const float* __restrict__ bih1, const float* __restrict__ bhh1,
    const float* __restrict__ Wout, const float* __restrict__ bout,
    float* __restrict__ out, unsigned* __restrict__ cnt,
    u16* __restrict__ h0h0, u16* __restrict__ h0h1,
    u16* __restrict__ h0l0, u16* __restrict__ h0l1,
    u16* __restrict__ h1h0, u16* __restrict__ h1h1,
    u16* __restrict__ h1l0, u16* __restrict__ h1l1,
    float* __restrict__ c0, float* __restrict__ c1)
{
  __shared__ u16 w0hh_h[8192], w0hh_l[8192];     // 16x512 bf16 hi/lo, swizzled
  __shared__ u16 w1ih_h[8192], w1ih_l[8192];
  __shared__ u16 w1hh_h[8192], w1hh_l[8192];
  __shared__ u16 wcmb_h[8192], wcmb_l[8192];
  __shared__ u16 w0ih_h[1024], w0ih_l[1024];     // 16x64
  __shared__ float gl[128*17];                   // gate exchange
  __shared__ float pr[128*2];                    // pred partials
  __shared__ float bs0[16], bs1[16], bsd[16];

  const int wg = blockIdx.x, tid = threadIdx.x;
  const int mhalf = wg & 1, jq = wg >> 1;        // 2 x 128 WGs
  const int lane = tid & 63, wv = tid >> 6;
  const int cI = lane & 15;
  const int kc = (lane >> 4) << 3;

  // ---- one-time init: stage + split weight slices into LDS ----
  load_slice(Whh0, 512, 9, 8192, w0hh_h, w0hh_l, jq, tid);
  load_slice(Wih1, 512, 9, 8192, w1ih_h, w1ih_l, jq, tid);
  load_slice(Whh1, 512, 9, 8192, w1hh_h, w1hh_l, jq, tid);
  load_slice(Wc,   512, 9, 8192, wcmb_h, wcmb_l, jq, tid);
  load_slice(Wih0,  64, 6, 1024, w0ih_h, w0ih_l, jq, tid);
  if (tid < 16){
    int n = ((tid >> 2) << 9) + jq*4 + (tid & 3);
    bs0[tid] = bih0[n] + bhh0[n];
    bs1[tid] = bih1[n] + bhh1[n];
    bsd[tid] = bb[n];
  }
  __syncthreads();

  const int ar0 = mhalf*128 + wv*32 + cI;        // M-tile 0 batch row
  const int ar1 = ar0 + 16;                      // M-tile 1
  const int aoff0 = ar0*512 + kc, aoff1 = ar1*512 + kc;

  u16* H0h[2] = { h0h0, h0h1 };  u16* H0l[2] = { h0l0, h0l1 };
  u16* H1h[2] = { h1h0, h1h1 };  u16* H1l[2] = { h1l0, h1l1 };

  const float* xb0 = x + ar0*21504;              // x[b][d][t]
  const float* xb1 = x + ar1*21504;

  unsigned ep = 0;

  for (int t = 0; t < 432; ++t){
    const int p = t & 1;
    const bool enc = (t < 336);

    // =============== phase A: layer 0 ===============
    f32x4 A0 = {0,0,0,0}, A1 = {0,0,0,0};
    if (enc){
      #pragma unroll
      for (int ks = 0; ks < 2; ++ks){            // x segment (K=64)
        int k = kc + ks*32;
        short8 a0h, a0l, a1h, a1l;
        #pragma unroll
        for (int j = 0; j < 8; ++j){
          HiLo s0 = split1(xb0[(k + j)*336 + t]); a0h[j] = s0.hi; a0l[j] = s0.lo;
          HiLo s1 = split1(xb1[(k + j)*336 + t]); a1h[j] = s1.hi; a1l[j] = s1.lo;
        }
        short8 bh = lds8(w0ih_h, cI, k, 128);
        short8 bl = lds8(w0ih_l, cI, k, 128);
        SMACC(A0, a0h, a0l, bh, bl);
        SMACC(A1, a1h, a1l, bh, bl);
      }
    } else if (t > 336){                         // Wcomb segment over h1_{t-1}
      const u16* hH = H1h[p^1]; const u16* hL = H1l[p^1];
      #pragma unroll 4
      for (int ks = 0; ks < 16; ++ks){
        int k = ks*32;
        short8 a0h = *(const short8*)(hH + aoff0 + k);
        short8 a0l = *(const short8*)(hL + aoff0 + k);
        short8 a1h = *(const short8*)(hH + aoff1 + k);
        short8 a1l = *(const short8*)(hL + aoff1 + k);
        short8 bh = lds8(wcmb_h, cI, kc + k, 1024);
        short8 bl = lds8(wcmb_l, cI, kc + k, 1024);
        SMACC(A0, a0h, a0l, bh, bl);
        SMACC(A1, a1h, a1l, bh, bl);
      }
    }
    {                                            // Whh0 segment over h0_{t-1}
      const u16* hH = H0h[p^1]; const u16* hL = H0l[p^1];
      #pragma unroll 4
      for (int ks = 0; ks < 16; ++ks){
        int k = ks*32;
        short8 a0h = *(const short8*)(hH + aoff0 + k);
        short8 a0l = *(const short8*)(hL + aoff0 + k);
        short8 a1h = *(const short8*)(hH + aoff1 + k);
        short8 a1l = *(const short8*)(hL + aoff1 + k);
        short8 bh = lds8(w0hh_h, cI, kc + k, 1024);
        short8 bl = lds8(w0hh_l, cI, kc + k, 1024);
        SMACC(A0, a0h, a0l, bh, bl);
        SMACC(A1, a1h, a1l, bh, bl);
      }
    }
    // decoder pred output l = t-337 from h1_{t-1} (WGs jq<64 own col d=jq)
    if (!enc && t > 336 && jq < 64){
      const int bl_ = tid & 127, q = tid >> 7;
      const int b = mhalf*128 + bl_;
      const u16* hH = H1h[p^1] + b*512 + q*256;
      const u16* hL = H1l[p^1] + b*512 + q*256;
      const float* wr = Wout + jq*512 + q*256;
      float part = 0.f;
      #pragma unroll 4
      for (int k = 0; k < 256; k += 8){
        short8 hv = *(const short8*)(hH + k);
        short8 lv = *(const short8*)(hL + k);
        #pragma unroll
        for (int j = 0; j < 8; ++j)
          part += (bf2f((u16)hv[j]) + bf2f((u16)lv[j])) * wr[k + j];
      }
      pr[bl_*2 + q] = part;
      __syncthreads();
      if (tid < 128){
        float v = pr[tid*2] + pr[tid*2 + 1] + bout[jq];
        out[131072 + ((mhalf*128 + tid)*64 + jq)*96 + (t - 337)] = v;
      }
    }
    // cell update A (h0, c0)
    {
      const float* bias = (enc || t == 336) ? bs0 : bsd;
      __syncthreads();
      const int rb = wv*32 + ((lane >> 4) << 2);
      #pragma unroll
      for (int r = 0; r < 4; ++r){
        gl[(rb + r)*17 + cI]      = A0[r] + bias[cI];
        gl[(rb + 16 + r)*17 + cI] = A1[r] + bias[cI];
      }
      __syncthreads();
      #pragma unroll
      for (int q = 0; q < 2; ++q){
        int e = tid + q*256;
        int m = e >> 2, cloc = e & 3;
        float iv = gl[m*17 + cloc];
        float fv = gl[m*17 + 4 + cloc];
        float gv = gl[m*17 + 8 + cloc];
        float ov = gl[m*17 + 12 + cloc];
        float si = 1.f/(1.f + expf(-iv));
        float sf = 1.f/(1.f + expf(-fv));
        float so = 1.f/(1.f + expf(-ov));
        int gi = (mhalf*128 + m)*512 + jq*4 + cloc;
        float cn = sf*c0[gi] + si*tanhf(gv);
        c0[gi] = cn;
        float h = so*tanhf(cn);
        u16 hh = f2bf(h);
        H0h[p][gi] = hh;
        H0l[p][gi] = f2bf(h - bf2f(hh));
      }
    }
    ++ep; gbar(cnt, ep*256u);

    // =============== phase B: layer 1 ===============
    A0 = (f32x4){0,0,0,0}; A1 = (f32x4){0,0,0,0};
    {
      const u16* hH = H0h[p]; const u16* hL = H0l[p];   // h0_t
      #pragma unroll 4
      for (int ks = 0; ks < 16; ++ks){
        int k = ks*32;
        short8 a0h = *(const short8*)(hH + aoff0 + k);
        short8 a0l = *(const short8*)(hL + aoff0 + k);
        short8 a1h = *(const short8*)(hH + aoff1 + k);
        short8 a1l = *(const short8*)(hL + aoff1 + k);
        short8 bh = lds8(w1ih_h, cI, kc + k, 1024);
        short8 bl = lds8(w1ih_l, cI, kc + k, 1024);
        SMACC(A0, a0h, a0l, bh, bl);
        SMACC(A1, a1h, a1l, bh, bl);
      }
    }
    {
      const u16* hH = H1h[p^1]; const u16* hL = H1l[p^1];  // h1_{t-1}
      #pragma unroll 4
      for (int ks = 0; ks < 16; ++ks){
        int k = ks*32;
        short8 a0h = *(const short8*)(hH + aoff0 + k);
        short8 a0l = *(const short8*)(hL + aoff0 + k);
        short8 a1h = *(const short8*)(hH + aoff1 + k);
        short8 a1l = *(const short8*)(hL + aoff1 + k);
        short8 bh = lds8(w1hh_h, cI, kc + k, 1024);
        short8 bl = lds8(w1hh_l, cI, kc + k, 1024);
        SMACC(A0, a0h, a0l, bh, bl);
        SMACC(A1, a1h, a1l, bh, bl);
      }
    }
    {
      float* gf = (t == 335) ? out : (float*)nullptr;
      __syncthreads();
      const int rb = wv*32 + ((lane >> 4) << 2);
      #pragma unroll
      for (int r = 0; r < 4; ++r){
        gl[(rb + r)*17 + cI]      = A0[r] + bs1[cI];
        gl[(rb + 16 + r)*17 + cI] = A1[r] + bs1[cI];
      }
      __syncthreads();
      #pragma unroll
      for (int q = 0; q < 2; ++q){
        int e = tid + q*256;
        int m = e >> 2, cloc = e & 3;
        float iv = gl[m*17 + cloc];
        float fv = gl[m*17 + 4 + cloc];
        float gv = gl[m*17 + 8 + cloc];
        float ov = gl[m*17 + 12 + cloc];
        float si = 1.f/(1.f + expf(-iv));
        float sf = 1.f/(1.f + expf(-fv));
        float so = 1.f/(1.f + expf(-ov));
        int gi = (mhalf*128 + m)*512 + jq*4 + cloc;
        float cn = sf*c1[gi] + si*tanhf(gv);
        c1[gi] = cn;
        float h = so*tanhf(cn);
        u16 hh = f2bf(h);
        H1h[p][gi] = hh;
        H1l[p][gi] = f2bf(h - bf2f(hh));
        if (gf) gf[gi] = h;
      }
    }
    ++ep; gbar(cnt, ep*256u);
  }
}

// ---- tail: pred for l=95 from h1_431 ---------------------------------------
__global__ void __launch_bounds__(256) pred_last(
    const u16* __restrict__ h1hi, const u16* __restrict__ h1lo,
    const float* __restrict__ Wout, const float* __restrict__ bout,
    float* __restrict__ out)
{
  const int wg = blockIdx.x, tid = threadIdx.x;
  const int bsub = tid >> 6, d = tid & 63;
  const int b = wg*4 + bsub;
  float acc = bout[d];
  const u16* hH = h1hi + b*512;
  const u16* hL = h1lo + b*512;
  const float* wr = Wout + d*512;
  #pragma unroll 8
  for (int k = 0; k < 512; k += 8){
    short8 hv = *(const short8*)(hH + k);
    short8 lv = *(const short8*)(hL + k);
    #pragma unroll
    for (int j = 0; j < 8; ++j)
      acc += (bf2f((u16)hv[j]) + bf2f((u16)lv[j])) * wr[k + j];
  }
  out[131072 + (b*64 + d)*96 + 95] = acc;
}

// ======================= fallback (R9 proven path) ==========================
__device__ __forceinline__ void cell_epilogue_fb(
    float* gl, const float* bs, float* __restrict__ cbuf,
    u16* __restrict__ hhi, u16* __restrict__ hlo,
    float* __restrict__ gfout, int mrow, int jblk,
    const f32x4& a0, const f32x4& a1, int wv, int lane, int tid)
{
  __syncthreads();
  const int rbase = wv*16 + ((lane >> 4) << 2);
  const int cI = lane & 15;
  #pragma unroll
  for (int r = 0; r < 4; ++r){
    gl[(rbase+r)*33 + cI]      = a0[r] + bs[cI];
    gl[(rbase+r)*33 + 16 + cI] = a1[r] + bs[16 + cI];
  }
  __syncthreads();
  #pragma unroll
  for (int q = 0; q < 2; ++q){
    int e = tid + q*256;
    int m = e >> 3, jj = e & 7;
    float iv = gl[m*33 + jj];
    float fv = gl[m*33 + 8 + jj];
    float gv = gl[m*33 + 16 + jj];
    float ov = gl[m*33 + 24 + jj];
    float si = 1.f/(1.f + expf(-iv));
    float sf = 1.f/(1.f + expf(-fv));
    float so = 1.f/(1.f + expf(-ov));
    int gi = (mrow*64 + m)*512 + jblk*8 + jj;
    float cn = sf*cbuf[gi] + si*tanhf(gv);
    cbuf[gi] = cn;
    float h = so*tanhf(cn);
    u16 hh = f2bf(h);
    hhi[gi] = hh;
    hlo[gi] = f2bf(h - bf2f(hh));
    if (gfout) gfout[gi] = h;
  }
}

template<bool ENC>
__global__ void __launch_bounds__(256) l0_fb(
    const float* __restrict__ x,
    const u16* __restrict__ predhi, const u16* __restrict__ predlo,
    const float* __restrict__ Wihf, const float* __restrict__ Whhf,
    const float* __restrict__ bih, const float* __restrict__ bhh,
    const u16* __restrict__ hphi, const u16* __restrict__ hplo,
    u16* __restrict__ hnhi, u16* __restrict__ hnlo,
    float* __restrict__ c0, int t)
{
  __shared__ float gl[64*33];
  __shared__ float bs[32];
  const int wg = blockIdx.x, tid = threadIdx.x;
  const int mrow = wg & 3, jblk = wg >> 2;
  const int lane = tid & 63, wv = tid >> 6;
  if (tid < 32){
    int n = ((tid >> 3) << 9) + jblk*8 + (tid & 7);
    bs[tid] = bih[n] + bhh[n];
  }
  const int ar = mrow*64 + wv*16 + (lane & 15);
  const int kc = (lane >> 4) << 3;
  const int cI = lane & 15;
  const int n0 = ((cI >> 3) << 9) + jblk*8 + (cI & 7);
  const int n1 = n0 + 1024;

  f32x4 acc0 = {0,0,0,0}, acc1 = {0,0,0,0};
  #pragma unroll
  for (int ks = 0; ks < 2; ++ks){
    int k = ks*32 + kc;
    short8 ah, al;
    if (ENC){
      const float* xb = x + ar*21504 + t;
      #pragma unroll
      for (int j = 0; j < 8; ++j){ HiLo s = split1(xb[(k + j)*336]); ah[j] = s.hi; al[j] = s.lo; }
    } else {
      ah = *(const short8*)(predhi + ar*64 + k);
      al = *(const short8*)(predlo + ar*64 + k);
    }
    short8 bh0, bl0, bh1, bl1;
    ldw8s(Wihf + n0*64 + k, bh0, bl0);
    ldw8s(Wihf + n1*64 + k, bh1, bl1);
    SMACC(acc0, ah, al, bh0, bl0);
    SMACC(acc1, ah, al, bh1, bl1);
  }
  const u16* hH = hphi + ar*512 + kc;
  const u16* hL = hplo + ar*512 + kc;
  #pragma unroll 4
  for (int ks = 0; ks < 16; ++ks){
    int k = ks*32;
    short8 ah = *(const short8*)(hH + k);
    short8 al = *(const short8*)(hL + k);
    short8 bh0, bl0, bh1, bl1;
    ldw8s(Whhf + n0*512 + kc + k, bh0, bl0);
    ldw8s(Whhf + n1*512 + kc + k, bh1, bl1);
    SMACC(acc0, ah, al, bh0, bl0);
    SMACC(acc1, ah, al, bh1, bl1);
  }
  cell_epilogue_fb(gl, bs, c0, hnhi, hnlo, nullptr, mrow, jblk, acc0, acc1, wv, lane, tid);
}

__global__ void __launch_bounds__(256) l1_fb(
    const float* __restrict__ Wihf, const float* __restrict__ Whhf,
    const float* __restrict__ bih, const float* __restrict__ bhh,
    const u16* __restrict__ h0hi, const u16* __restrict__ h0lo,
    const u16* __restrict__ h1phi, const u16* __restrict__ h1plo,
    u16* __restrict__ h1nhi, u16* __restrict__ h1nlo,
    float* __restrict__ c1, float* __restrict__ gfout)
{
  __shared__ float gl[64*33];
  __shared__ float bs[32];
  const int wg = blockIdx.x, tid = threadIdx.x;
  const int mrow = wg & 3, jblk = wg >> 2;
  const int lane = tid & 63, wv = tid >> 6;
  if (tid < 32){
    int n = ((tid >> 3) << 9) + jblk*8 + (tid & 7);
    bs[tid] = bih[n] + bhh[n];
  }
  const int ar = mrow*64 + wv*16 + (lane & 15);
  const int kc = (lane >> 4) << 3;
  const int cI = lane & 15;
  const int n0 = ((cI >> 3) << 9) + jblk*8 + (cI & 7);
  const int n1 = n0 + 1024;

  f32x4 acc0 = {0,0,0,0}, acc1 = {0,0,0,0};
  {
    const u16* hH = h0hi + ar*512 + kc;
    const u16* hL = h0lo + ar*512 + kc;
    #pragma unroll 4
    for (int ks = 0; ks < 16; ++ks){
      int k = ks*32;
      short8 ah = *(const short8*)(hH + k);
      short8 al = *(const short8*)(hL + k);
      short8 bh0, bl0, bh1, bl1;
      ldw8s(Wihf + n0*512 + kc + k, bh0, bl0);
      ldw8s(Wihf + n1*512 + kc + k, bh1, bl1);
      SMACC(acc0, ah, al, bh0, bl0);
      SMACC(acc1, ah, al, bh1, bl1);
    }
  }
  {
    const u16* hH = h1phi + ar*512 + kc;
    const u16* hL = h1plo + ar*512 + kc;
    #pragma unroll 4
    for (int ks = 0; ks < 16; ++ks){
      int k = ks*32;
      short8 ah = *(const short8*)(hH + k);
      short8 al = *(const short8*)(hL + k);
      short8 bh0, bl0, bh1, bl1;
      ldw8s(Whhf + n0*512 + kc + k, bh0, bl0);
      ldw8s(Whhf + n1*512 + kc + k, bh1, bl1);
      SMACC(acc0, ah, al, bh0, bl0);
      SMACC(acc1, ah, al, bh1, bl1);
    }
  }
  cell_epilogue_fb(gl, bs, c1, h1nhi, h1nlo, gfout, mrow, jblk, acc0, acc1, wv, lane, tid);
}

__global__ void __launch_bounds__(256) pred_fb(
    const u16* __restrict__ h1hi, const u16* __restrict__ h1lo,
    const float* __restrict__ Wout, const float* __restrict__ bout,
    u16* __restrict__ predhi, u16* __restrict__ predlo,
    float* __restrict__ out, int l)
{
  const int wg = blockIdx.x, tid = threadIdx.x;
  const int bsub = tid >> 6, d = tid & 63;
  const int b = wg*4 + bsub;
  float acc = bout[d];
  const u16* hH = h1hi + b*512;
  const u16* hL = h1lo + b*512;
  const float* wr = Wout + d*512;
  #pragma unroll 8
  for (int k = 0; k < 512; k += 8){
    short8 hv = *(const short8*)(hH + k);
    short8 lv = *(const short8*)(hL + k);
    #pragma unroll
    for (int j = 0; j < 8; ++j)
      acc += (bf2f((u16)hv[j]) + bf2f((u16)lv[j])) * wr[k + j];
  }
  HiLo s = split1(acc);
  predhi[b*64 + d] = (u16)s.hi;
  predlo[b*64 + d] = (u16)s.lo;
  out[131072 + (b*64 + d)*96 + l] = acc;
}

extern "C" void kernel_launch(void* const* d_in, const int* in_sizes, int n_in,
                              void* d_out, int out_size, void* d_ws, size_t ws_size,
                              hipStream_t stream)
{
  const float* x    = (const float*)d_in[0];
  const float* Wih0 = (const float*)d_in[1];
  const float* Whh0 = (const float*)d_in[2];
  const float* bih0 = (const float*)d_in[3];
  const float* bhh0 = (const float*)d_in[4];
  const float* Wih1 = (const float*)d_in[5];
  const float* Whh1 = (const float*)d_in[6];
  const float* bih1 = (const float*)d_in[7];
  const float* bhh1 = (const float*)d_in[8];
  const float* Wout = (const float*)d_in[9];
  const float* bout = (const float*)d_in[10];
  float* out = (float*)d_out;

  // ---- ws layout: state 3.07 MB + Wcomb 4 MB + bb 8 KB
  char* ws = (char*)d_ws;
  u16* h0h[2] = { (u16*)(ws + 0),       (u16*)(ws + 262144) };
  u16* h0l[2] = { (u16*)(ws + 524288),  (u16*)(ws + 786432) };
  u16* h1h[2] = { (u16*)(ws + 1048576), (u16*)(ws + 1310720) };
  u16* h1l[2] = { (u16*)(ws + 1572864), (u16*)(ws + 1835008) };
  float* c0   = (float*)(ws + 2097152);
  float* c1   = (float*)(ws + 2621440);
  unsigned* cnt = (unsigned*)(ws + 3145728);      // main path
  u16* predh  = (u16*)(ws + 3145728);             // fallback path
  u16* predl  = (u16*)(ws + 3178496);
  float* Wc   = (float*)(ws + 3211264);           // 2048x512 f32
  float* bb   = (float*)(ws + 3211264 + 4194304);
  const size_t NEED = 3211264u + 4194304u + 8192u;
  const bool ps = (ws_size >= NEED);

  (void)hipMemsetAsync(d_ws, 0, 3211264, stream);   // state + cnt/predbf

  if (ps){
    wcomb_k<<<dim3(256), dim3(256), 0, stream>>>(Wih0, Wout, bout, bih0, bhh0, Wc, bb);
    lstm_persist<<<dim3(256), dim3(256), 0, stream>>>(
        x, Whh0, Wih0, Wih1, Whh1, Wc, bb,
        bih0, bhh0, bih1, bhh1, Wout, bout,
        out, cnt,
        h0h[0], h0h[1], h0l[0], h0l[1], h1h[0], h1h[1], h1l[0], h1l[1],
        c0, c1);
    pred_last<<<dim3(64), dim3(256), 0, stream>>>(h1h[1], h1l[1], Wout, bout, out);
  } else {
    for (int t = 0; t < 432; ++t){
      const int p = t & 1;
      float* gf = (t == 335) ? out : (float*)nullptr;
      if (t < 336)
        l0_fb<true><<<dim3(256), dim3(256), 0, stream>>>(
            x, predh, predl, Wih0, Whh0, bih0, bhh0,
            h0h[p^1], h0l[p^1], h0h[p], h0l[p], c0, t);
      else
        l0_fb<false><<<dim3(256), dim3(256), 0, stream>>>(
            x, predh, predl, Wih0, Whh0, bih0, bhh0,
            h0h[p^1], h0l[p^1], h0h[p], h0l[p], c0, t);
      l1_fb<<<dim3(256), dim3(256), 0, stream>>>(
          Wih1, Whh1, bih1, bhh1, h0h[p], h0l[p],
          h1h[p^1], h1l[p^1], h1h[p], h1l[p], c1, gf);
      if (t >= 336)
        pred_fb<<<dim3(64), dim3(256), 0, stream>>>(
            h1h[p], h1l[p], Wout, bout, predh, predl, out, t - 336);
    }
  }
}

// Round 12
// 34385.837 us; speedup vs baseline: 1.3307x; 1.3307x over previous
//
#include <hip/hip_runtime.h>

typedef unsigned short u16;
typedef __attribute__((ext_vector_type(8))) short short8;
typedef __attribute__((ext_vector_type(4))) float f32x4;

__device__ __forceinline__ float bf2f(u16 v){
  union { unsigned u; float f; } t; t.u = ((unsigned)v) << 16; return t.f;
}
__device__ __forceinline__ u16 f2bf(float f){
  union { float f; unsigned u; } t; t.f = f;
  unsigned u = t.u;
  return (u16)((u + 0x7fffu + ((u >> 16) & 1u)) >> 16);
}
struct HiLo { short hi, lo; };
__device__ __forceinline__ HiLo split1(float v){
  HiLo r;
  u16 h = f2bf(v);
  r.hi = (short)h;
  r.lo = (short)f2bf(v - bf2f(h));
  return r;
}
__device__ __forceinline__ void ldw8s(const float* __restrict__ p, short8& hi, short8& lo){
  #pragma unroll
  for (int j = 0; j < 8; ++j){ HiLo s = split1(p[j]); hi[j] = s.hi; lo[j] = s.lo; }
}

#define MFMA(acc, a, b) acc = __builtin_amdgcn_mfma_f32_16x16x32_bf16(a, b, acc, 0,0,0)
#define SMACC(acc, ah, al, bh, bl) do{ MFMA(acc, ah, bh); MFMA(acc, ah, bl); MFMA(acc, al, bh); }while(0)

// ---- prepass: Wcomb = Wih0 @ Wout (2048x512 f32), bb = bih0+bhh0+Wih0@bout -
__global__ void __launch_bounds__(256) wcomb_k(
    const float* __restrict__ Wih0, const float* __restrict__ Wout,
    const float* __restrict__ bout, const float* __restrict__ bih0,
    const float* __restrict__ bhh0,
    float* __restrict__ Wc, float* __restrict__ bb)
{
  __shared__ float wl[8*64];
  __shared__ float bo[64];
  const int wg = blockIdx.x, tid = threadIdx.x;
  const int r0 = wg*8;
  for (int i = tid; i < 512; i += 256) wl[i] = Wih0[(r0 + (i >> 6))*64 + (i & 63)];
  if (tid < 64) bo[tid] = bout[tid];
  __syncthreads();
  if (tid < 8){
    int n = r0 + tid;
    float a = bih0[n] + bhh0[n];
    #pragma unroll 8
    for (int d = 0; d < 64; ++d) a += wl[tid*64 + d]*bo[d];
    bb[n] = a;
  }
  #pragma unroll
  for (int jj = 0; jj < 2; ++jj){
    int j = tid + jj*256;
    float acc[8] = {0,0,0,0,0,0,0,0};
    for (int d = 0; d < 64; ++d){
      float wv = Wout[d*512 + j];
      #pragma unroll
      for (int r = 0; r < 8; ++r) acc[r] += wl[r*64 + d]*wv;
    }
    #pragma unroll
    for (int r = 0; r < 8; ++r) Wc[(r0 + r)*512 + j] = acc[r];
  }
}

// ---- grid barrier: RELAXED polls (no per-poll cache invalidate!) -----------
// release: __threadfence (wb) BEFORE add; acquire: one __threadfence AFTER exit.
__device__ __forceinline__ void gbar(unsigned* cnt, unsigned target){
  __syncthreads();
  if (threadIdx.x == 0){
    __threadfence();    // release: drain + writeback prior stores (cross-XCD)
    __hip_atomic_fetch_add(cnt, 1u, __ATOMIC_RELAXED, __HIP_MEMORY_SCOPE_AGENT);
    while (__hip_atomic_load(cnt, __ATOMIC_RELAXED, __HIP_MEMORY_SCOPE_AGENT) < target)
      __builtin_amdgcn_s_sleep(2);
    __threadfence();    // acquire: one invalidate before reading peers' data
  }
  __syncthreads();
}

// ---- LDS weight-slice helpers (XOR-swizzled, G4) ---------------------------
__device__ __forceinline__ short8 lds8(const u16* base, int r, int kelem, int rowbytes){
  int bo = r*rowbytes + (((kelem*2)) ^ ((r & 7) << 4));
  return *(const short8*)((const char*)base + bo);
}
__device__ __forceinline__ void load_slice(
    const float* __restrict__ W, int ldw, int rowshift, int nelem,
    u16* lh, u16* ll, int jq, int tid)
{
  const int rowbytes = ldw*2;
  for (int i = tid; i < nelem; i += 256){
    int r = i >> rowshift, k = i & ((1 << rowshift) - 1);
    int n = ((r >> 2) << 9) + jq*4 + (r & 3);     // gate=(r>>2), col=jq*4+(r&3)
    HiLo s = split1(W[n*ldw + k]);
    int bo = r*rowbytes + (((k*2)) ^ ((r & 7) << 4));
    *(u16*)((char*)lh + bo) = (u16)s.hi;
    *(u16*)((char*)ll + bo) = (u16)s.lo;
  }
}

// ---- persistent kernel: all weights LDS-resident ---------------------------
// WG = (mhalf, jq): 128 batch rows x 4 hidden cols (16 gate rows).
__global__ void __launch_bounds__(256, 1) lstm_persist(
    const float* __restrict__ x,
    const float* __restrict__ Whh0, const float* __restrict__ Wih0,
    const float* __restrict__ Wih1, const float* __restrict__ Whh1,
    const float* __restrict__ Wc,   const float* __restrict__ bb,
    const float* __restrict__ bih0, const float* __restrict__ bhh0,
    const float* __restrict__ bih1, const float* __restrict__ bhh1,
    const float* __restrict__ Wout, const float* __restrict__ bout,
    float* __restrict__ out, unsigned* __restrict__ cnt,
    u16* __restrict__ h0h0, u16* __restrict__ h0h1,
    u16* __restrict__ h0l0, u16* __restrict__ h0l1,
    u16* __restrict__ h1h0, u16* __restrict__ h1h1,
    u16* __restrict__ h1l0, u16* __restrict__ h1l1,
    float* __restrict__ c0, float* __restrict__ c1)
{
  __shared__ u16 w0hh_h[8192], w0hh_l[8192];     // 16x512 bf16 hi/lo, swizzled
  __shared__ u16 w1ih_h[8192], w1ih_l[8192];
  __shared__ u16 w1hh_h[8192], w1hh_l[8192];
  __shared__ u16 wcmb_h[8192], wcmb_l[8192];
  __shared__ u16 w0ih_h[1024], w0ih_l[1024];     // 16x64
  __shared__ float gl[128*17];                   // gate exchange
  __shared__ float pr[128*2];                    // pred partials
  __shared__ float bs0[16], bs1[16], bsd[16];

  const int wg = blockIdx.x, tid = threadIdx.x;
  const int mhalf = wg & 1, jq = wg >> 1;        // 2 x 128 WGs
  const int lane = tid & 63, wv = tid >> 6;
  const int cI = lane & 15;
  const int kc = (lane >> 4) << 3;

  // ---- one-time init: stage + split weight slices into LDS ----
  load_slice(Whh0, 512, 9, 8192, w0hh_h, w0hh_l, jq, tid);
  load_slice(Wih1, 512, 9, 8192, w1ih_h, w1ih_l, jq, tid);
  load_slice(Whh1, 512, 9, 8192, w1hh_h, w1hh_l, jq, tid);
  load_slice(Wc,   512, 9, 8192, wcmb_h, wcmb_l, jq, tid);
  load_slice(Wih0,  64, 6, 1024, w0ih_h, w0ih_l, jq, tid);
  if (tid < 16){
    int n = ((tid >> 2) << 9) + jq*4 + (tid & 3);
    bs0[tid] = bih0[n] + bhh0[n];
    bs1[tid] = bih1[n] + bhh1[n];
    bsd[tid] = bb[n];
  }
  __syncthreads();

  const int ar0 = mhalf*128 + wv*32 + cI;        // M-tile 0 batch row
  const int ar1 = ar0 + 16;                      // M-tile 1
  const int aoff0 = ar0*512 + kc, aoff1 = ar1*512 + kc;

  u16* H0h[2] = { h0h0, h0h1 };  u16* H0l[2] = { h0l0, h0l1 };
  u16* H1h[2] = { h1h0, h1h1 };  u16* H1l[2] = { h1l0, h1l1 };

  const float* xb0 = x + ar0*21504;              // x[b][d][t]
  const float* xb1 = x + ar1*21504;

  unsigned ep = 0;

  for (int t = 0; t < 432; ++t){
    const int p = t & 1;
    const bool enc = (t < 336);

    // =============== phase A: layer 0 ===============
    f32x4 A0 = {0,0,0,0}, A1 = {0,0,0,0};
    if (enc){
      #pragma unroll
      for (int ks = 0; ks < 2; ++ks){            // x segment (K=64)
        int k = kc + ks*32;
        short8 a0h, a0l, a1h, a1l;
        #pragma unroll
        for (int j = 0; j < 8; ++j){
          HiLo s0 = split1(xb0[(k + j)*336 + t]); a0h[j] = s0.hi; a0l[j] = s0.lo;
          HiLo s1 = split1(xb1[(k + j)*336 + t]); a1h[j] = s1.hi; a1l[j] = s1.lo;
        }
        short8 bh = lds8(w0ih_h, cI, k, 128);
        short8 bl = lds8(w0ih_l, cI, k, 128);
        SMACC(A0, a0h, a0l, bh, bl);
        SMACC(A1, a1h, a1l, bh, bl);
      }
    } else if (t > 336){                         // Wcomb segment over h1_{t-1}
      const u16* hH = H1h[p^1]; const u16* hL = H1l[p^1];
      #pragma unroll 4
      for (int ks = 0; ks < 16; ++ks){
        int k = ks*32;
        short8 a0h = *(const short8*)(hH + aoff0 + k);
        short8 a0l = *(const short8*)(hL + aoff0 + k);
        short8 a1h = *(const short8*)(hH + aoff1 + k);
        short8 a1l = *(const short8*)(hL + aoff1 + k);
        short8 bh = lds8(wcmb_h, cI, kc + k, 1024);
        short8 bl = lds8(wcmb_l, cI, kc + k, 1024);
        SMACC(A0, a0h, a0l, bh, bl);
        SMACC(A1, a1h, a1l, bh, bl);
      }
    }
    {                                            // Whh0 segment over h0_{t-1}
      const u16* hH = H0h[p^1]; const u16* hL = H0l[p^1];
      #pragma unroll 4
      for (int ks = 0; ks < 16; ++ks){
        int k = ks*32;
        short8 a0h = *(const short8*)(hH + aoff0 + k);
        short8 a0l = *(const short8*)(hL + aoff0 + k);
        short8 a1h = *(const short8*)(hH + aoff1 + k);
        short8 a1l = *(const short8*)(hL + aoff1 + k);
        short8 bh = lds8(w0hh_h, cI, kc + k, 1024);
        short8 bl = lds8(w0hh_l, cI, kc + k, 1024);
        SMACC(A0, a0h, a0l, bh, bl);
        SMACC(A1, a1h, a1l, bh, bl);
      }
    }
    // decoder pred output l = t-337 from h1_{t-1} (WGs jq<64 own col d=jq)
    if (!enc && t > 336 && jq < 64){
      const int bl_ = tid & 127, q = tid >> 7;
      const int b = mhalf*128 + bl_;
      const u16* hH = H1h[p^1] + b*512 + q*256;
      const u16* hL = H1l[p^1] + b*512 + q*256;
      const float* wr = Wout + jq*512 + q*256;
      float part = 0.f;
      #pragma unroll 4
      for (int k = 0; k < 256; k += 8){
        short8 hv = *(const short8*)(hH + k);
        short8 lv = *(const short8*)(hL + k);
        #pragma unroll
        for (int j = 0; j < 8; ++j)
          part += (bf2f((u16)hv[j]) + bf2f((u16)lv[j])) * wr[k + j];
      }
      pr[bl_*2 + q] = part;
      __syncthreads();
      if (tid < 128){
        float v = pr[tid*2] + pr[tid*2 + 1] + bout[jq];
        out[131072 + ((mhalf*128 + tid)*64 + jq)*96 + (t - 337)] = v;
      }
    }
    // cell update A (h0, c0)
    {
      const float* bias = (enc || t == 336) ? bs0 : bsd;
      __syncthreads();
      const int rb = wv*32 + ((lane >> 4) << 2);
      #pragma unroll
      for (int r = 0; r < 4; ++r){
        gl[(rb + r)*17 + cI]      = A0[r] + bias[cI];
        gl[(rb + 16 + r)*17 + cI] = A1[r] + bias[cI];
      }
      __syncthreads();
      #pragma unroll
      for (int q = 0; q < 2; ++q){
        int e = tid + q*256;
        int m = e >> 2, cloc = e & 3;
        float iv = gl[m*17 + cloc];
        float fv = gl[m*17 + 4 + cloc];
        float gv = gl[m*17 + 8 + cloc];
        float ov = gl[m*17 + 12 + cloc];
        float si = 1.f/(1.f + expf(-iv));
        float sf = 1.f/(1.f + expf(-fv));
        float so = 1.f/(1.f + expf(-ov));
        int gi = (mhalf*128 + m)*512 + jq*4 + cloc;
        float cn = sf*c0[gi] + si*tanhf(gv);
        c0[gi] = cn;
        float h = so*tanhf(cn);
        u16 hh = f2bf(h);
        H0h[p][gi] = hh;
        H0l[p][gi] = f2bf(h - bf2f(hh));
      }
    }
    ++ep; gbar(cnt, ep*256u);

    // =============== phase B: layer 1 ===============
    A0 = (f32x4){0,0,0,0}; A1 = (f32x4){0,0,0,0};
    {
      const u16* hH = H0h[p]; const u16* hL = H0l[p];   // h0_t
      #pragma unroll 4
      for (int ks = 0; ks < 16; ++ks){
        int k = ks*32;
        short8 a0h = *(const short8*)(hH + aoff0 + k);
        short8 a0l = *(const short8*)(hL + aoff0 + k);
        short8 a1h = *(const short8*)(hH + aoff1 + k);
        short8 a1l = *(const short8*)(hL + aoff1 + k);
        short8 bh = lds8(w1ih_h, cI, kc + k, 1024);
        short8 bl = lds8(w1ih_l, cI, kc + k, 1024);
        SMACC(A0, a0h, a0l, bh, bl);
        SMACC(A1, a1h, a1l, bh, bl);
      }
    }
    {
      const u16* hH = H1h[p^1]; const u16* hL = H1l[p^1];  // h1_{t-1}
      #pragma unroll 4
      for (int ks = 0; ks < 16; ++ks){
        int k = ks*32;
        short8 a0h = *(const short8*)(hH + aoff0 + k);
        short8 a0l = *(const short8*)(hL + aoff0 + k);
        short8 a1h = *(const short8*)(hH + aoff1 + k);
        short8 a1l = *(const short8*)(hL + aoff1 + k);
        short8 bh = lds8(w1hh_h, cI, kc + k, 1024);
        short8 bl = lds8(w1hh_l, cI, kc + k, 1024);
        SMACC(A0, a0h, a0l, bh, bl);
        SMACC(A1, a1h, a1l, bh, bl);
      }
    }
    {
      float* gf = (t == 335) ? out : (float*)nullptr;
      __syncthreads();
      const int rb = wv*32 + ((lane >> 4) << 2);
      #pragma unroll
      for (int r = 0; r < 4; ++r){
        gl[(rb + r)*17 + cI]      = A0[r] + bs1[cI];
        gl[(rb + 16 + r)*17 + cI] = A1[r] + bs1[cI];
      }
      __syncthreads();
      #pragma unroll
      for (int q = 0; q < 2; ++q){
        int e = tid + q*256;
        int m = e >> 2, cloc = e & 3;
        float iv = gl[m*17 + cloc];
        float fv = gl[m*17 + 4 + cloc];
        float gv = gl[m*17 + 8 + cloc];
        float ov = gl[m*17 + 12 + cloc];
        float si = 1.f/(1.f + expf(-iv));
        float sf = 1.f/(1.f + expf(-fv));
        float so = 1.f/(1.f + expf(-ov));
        int gi = (mhalf*128 + m)*512 + jq*4 + cloc;
        float cn = sf*c1[gi] + si*tanhf(gv);
        c1[gi] = cn;
        float h = so*tanhf(cn);
        u16 hh = f2bf(h);
        H1h[p][gi] = hh;
        H1l[p][gi] = f2bf(h - bf2f(hh));
        if (gf) gf[gi] = h;
      }
    }
    ++ep; gbar(cnt, ep*256u);
  }
}

// ---- tail: pred for l=95 from h1_431 ---------------------------------------
__global__ void __launch_bounds__(256) pred_last(
    const u16* __restrict__ h1hi, const u16* __restrict__ h1lo,
    const float* __restrict__ Wout, const float* __restrict__ bout,
    float* __restrict__ out)
{
  const int wg = blockIdx.x, tid = threadIdx.x;
  const int bsub = tid >> 6, d = tid & 63;
  const int b = wg*4 + bsub;
  float acc = bout[d];
  const u16* hH = h1hi + b*512;
  const u16* hL = h1lo + b*512;
  const float* wr = Wout + d*512;
  #pragma unroll 8
  for (int k = 0; k < 512; k += 8){
    short8 hv = *(const short8*)(hH + k);
    short8 lv = *(const short8*)(hL + k);
    #pragma unroll
    for (int j = 0; j < 8; ++j)
      acc += (bf2f((u16)hv[j]) + bf2f((u16)lv[j])) * wr[k + j];
  }
  out[131072 + (b*64 + d)*96 + 95] = acc;
}

// ======================= fallback (R9 proven path) ==========================
__device__ __forceinline__ void cell_epilogue_fb(
    float* gl, const float* bs, float* __restrict__ cbuf,
    u16* __restrict__ hhi, u16* __restrict__ hlo,
    float* __restrict__ gfout, int mrow, int jblk,
    const f32x4& a0, const f32x4& a1, int wv, int lane, int tid)
{
  __syncthreads();
  const int rbase = wv*16 + ((lane >> 4) << 2);
  const int cI = lane & 15;
  #pragma unroll
  for (int r = 0; r < 4; ++r){
    gl[(rbase+r)*33 + cI]      = a0[r] + bs[cI];
    gl[(rbase+r)*33 + 16 + cI] = a1[r] + bs[16 + cI];
  }
  __syncthreads();
  #pragma unroll
  for (int q = 0; q < 2; ++q){
    int e = tid + q*256;
    int m = e >> 3, jj = e & 7;
    float iv = gl[m*33 + jj];
    float fv = gl[m*33 + 8 + jj];
    float gv = gl[m*33 + 16 + jj];
    float ov = gl[m*33 + 24 + jj];
    float si = 1.f/(1.f + expf(-iv));
    float sf = 1.f/(1.f + expf(-fv));
    float so = 1.f/(1.f + expf(-ov));
    int gi = (mrow*64 + m)*512 + jblk*8 + jj;
    float cn = sf*cbuf[gi] + si*tanhf(gv);
    cbuf[gi] = cn;
    float h = so*tanhf(cn);
    u16 hh = f2bf(h);
    hhi[gi] = hh;
    hlo[gi] = f2bf(h - bf2f(hh));
    if (gfout) gfout[gi] = h;
  }
}

template<bool ENC>
__global__ void __launch_bounds__(256) l0_fb(
    const float* __restrict__ x,
    const u16* __restrict__ predhi, const u16* __restrict__ predlo,
    const float* __restrict__ Wihf, const float* __restrict__ Whhf,
    const float* __restrict__ bih, const float* __restrict__ bhh,
    const u16* __restrict__ hphi, const u16* __restrict__ hplo,
    u16* __restrict__ hnhi, u16* __restrict__ hnlo,
    float* __restrict__ c0, int t)
{
  __shared__ float gl[64*33];
  __shared__ float bs[32];
  const int wg = blockIdx.x, tid = threadIdx.x;
  const int mrow = wg & 3, jblk = wg >> 2;
  const int lane = tid & 63, wv = tid >> 6;
  if (tid < 32){
    int n = ((tid >> 3) << 9) + jblk*8 + (tid & 7);
    bs[tid] = bih[n] + bhh[n];
  }
  const int ar = mrow*64 + wv*16 + (lane & 15);
  const int kc = (lane >> 4) << 3;
  const int cI = lane & 15;
  const int n0 = ((cI >> 3) << 9) + jblk*8 + (cI & 7);
  const int n1 = n0 + 1024;

  f32x4 acc0 = {0,0,0,0}, acc1 = {0,0,0,0};
  #pragma unroll
  for (int ks = 0; ks < 2; ++ks){
    int k = ks*32 + kc;
    short8 ah, al;
    if (ENC){
      const float* xb = x + ar*21504 + t;
      #pragma unroll
      for (int j = 0; j < 8; ++j){ HiLo s = split1(xb[(k + j)*336]); ah[j] = s.hi; al[j] = s.lo; }
    } else {
      ah = *(const short8*)(predhi + ar*64 + k);
      al = *(const short8*)(predlo + ar*64 + k);
    }
    short8 bh0, bl0, bh1, bl1;
    ldw8s(Wihf + n0*64 + k, bh0, bl0);
    ldw8s(Wihf + n1*64 + k, bh1, bl1);
    SMACC(acc0, ah, al, bh0, bl0);
    SMACC(acc1, ah, al, bh1, bl1);
  }
  const u16* hH = hphi + ar*512 + kc;
  const u16* hL = hplo + ar*512 + kc;
  #pragma unroll 4
  for (int ks = 0; ks < 16; ++ks){
    int k = ks*32;
    short8 ah = *(const short8*)(hH + k);
    short8 al = *(const short8*)(hL + k);
    short8 bh0, bl0, bh1, bl1;
    ldw8s(Whhf + n0*512 + kc + k, bh0, bl0);
    ldw8s(Whhf + n1*512 + kc + k, bh1, bl1);
    SMACC(acc0, ah, al, bh0, bl0);
    SMACC(acc1, ah, al, bh1, bl1);
  }
  cell_epilogue_fb(gl, bs, c0, hnhi, hnlo, nullptr, mrow, jblk, acc0, acc1, wv, lane, tid);
}

__global__ void __launch_bounds__(256) l1_fb(
    const float* __restrict__ Wihf, const float* __restrict__ Whhf,
    const float* __restrict__ bih, const float* __restrict__ bhh,
    const u16* __restrict__ h0hi, const u16* __restrict__ h0lo,
    const u16* __restrict__ h1phi, const u16* __restrict__ h1plo,
    u16* __restrict__ h1nhi, u16* __restrict__ h1nlo,
    float* __restrict__ c1, float* __restrict__ gfout)
{
  __shared__ float gl[64*33];
  __shared__ float bs[32];
  const int wg = blockIdx.x, tid = threadIdx.x;
  const int mrow = wg & 3, jblk = wg >> 2;
  const int lane = tid & 63, wv = tid >> 6;
  if (tid < 32){
    int n = ((tid >> 3) << 9) + jblk*8 + (tid & 7);
    bs[tid] = bih[n] + bhh[n];
  }
  const int ar = mrow*64 + wv*16 + (lane & 15);
  const int kc = (lane >> 4) << 3;
  const int cI = lane & 15;
  const int n0 = ((cI >> 3) << 9) + jblk*8 + (cI & 7);
  const int n1 = n0 + 1024;

  f32x4 acc0 = {0,0,0,0}, acc1 = {0,0,0,0};
  {
    const u16* hH = h0hi + ar*512 + kc;
    const u16* hL = h0lo + ar*512 + kc;
    #pragma unroll 4
    for (int ks = 0; ks < 16; ++ks){
      int k = ks*32;
      short8 ah = *(const short8*)(hH + k);
      short8 al = *(const short8*)(hL + k);
      short8 bh0, bl0, bh1, bl1;
      ldw8s(Wihf + n0*512 + kc + k, bh0, bl0);
      ldw8s(Wihf + n1*512 + kc + k, bh1, bl1);
      SMACC(acc0, ah, al, bh0, bl0);
      SMACC(acc1, ah, al, bh1, bl1);
    }
  }
  {
    const u16* hH = h1phi + ar*512 + kc;
    const u16* hL = h1plo + ar*512 + kc;
    #pragma unroll 4
    for (int ks = 0; ks < 16; ++ks){
      int k = ks*32;
      short8 ah = *(const short8*)(hH + k);
      short8 al = *(const short8*)(hL + k);
      short8 bh0, bl0, bh1, bl1;
      ldw8s(Whhf + n0*512 + kc + k, bh0, bl0);
      ldw8s(Whhf + n1*512 + kc + k, bh1, bl1);
      SMACC(acc0, ah, al, bh0, bl0);
      SMACC(acc1, ah, al, bh1, bl1);
    }
  }
  cell_epilogue_fb(gl, bs, c1, h1nhi, h1nlo, gfout, mrow, jblk, acc0, acc1, wv, lane, tid);
}

__global__ void __launch_bounds__(256) pred_fb(
    const u16* __restrict__ h1hi, const u16* __restrict__ h1lo,
    const float* __restrict__ Wout, const float* __restrict__ bout,
    u16* __restrict__ predhi, u16* __restrict__ predlo,
    float* __restrict__ out, int l)
{
  const int wg = blockIdx.x, tid = threadIdx.x;
  const int bsub = tid >> 6, d = tid & 63;
  const int b = wg*4 + bsub;
  float acc = bout[d];
  const u16* hH = h1hi + b*512;
  const u16* hL = h1lo + b*512;
  const float* wr = Wout + d*512;
  #pragma unroll 8
  for (int k = 0; k < 512; k += 8){
    short8 hv = *(const short8*)(hH + k);
    short8 lv = *(const short8*)(hL + k);
    #pragma unroll
    for (int j = 0; j < 8; ++j)
      acc += (bf2f((u16)hv[j]) + bf2f((u16)lv[j])) * wr[k + j];
  }
  HiLo s = split1(acc);
  predhi[b*64 + d] = (u16)s.hi;
  predlo[b*64 + d] = (u16)s.lo;
  out[131072 + (b*64 + d)*96 + l] = acc;
}

extern "C" void kernel_launch(void* const* d_in, const int* in_sizes, int n_in,
                              void* d_out, int out_size, void* d_ws, size_t ws_size,
                              hipStream_t stream)
{
  const float* x    = (const float*)d_in[0];
  const float* Wih0 = (const float*)d_in[1];
  const float* Whh0 = (const float*)d_in[2];
  const float* bih0 = (const float*)d_in[3];
  const float* bhh0 = (const float*)d_in[4];
  const float* Wih1 = (const float*)d_in[5];
  const float* Whh1 = (const float*)d_in[6];
  const float* bih1 = (const float*)d_in[7];
  const float* bhh1 = (const float*)d_in[8];
  const float* Wout = (const float*)d_in[9];
  const float* bout = (const float*)d_in[10];
  float* out = (float*)d_out;

  // ---- ws layout: state 3.07 MB + Wcomb 4 MB + bb 8 KB
  char* ws = (char*)d_ws;
  u16* h0h[2] = { (u16*)(ws + 0),       (u16*)(ws + 262144) };
  u16* h0l[2] = { (u16*)(ws + 524288),  (u16*)(ws + 786432) };
  u16* h1h[2] = { (u16*)(ws + 1048576), (u16*)(ws + 1310720) };
  u16* h1l[2] = { (u16*)(ws + 1572864), (u16*)(ws + 1835008) };
  float* c0   = (float*)(ws + 2097152);
  float* c1   = (float*)(ws + 2621440);
  unsigned* cnt = (unsigned*)(ws + 3145728);      // main path
  u16* predh  = (u16*)(ws + 3145728);             // fallback path
  u16* predl  = (u16*)(ws + 3178496);
  float* Wc   = (float*)(ws + 3211264);           // 2048x512 f32
  float* bb   = (float*)(ws + 3211264 + 4194304);
  const size_t NEED = 3211264u + 4194304u + 8192u;
  const bool ps = (ws_size >= NEED);

  (void)hipMemsetAsync(d_ws, 0, 3211264, stream);   // state + cnt/predbf

  if (ps){
    wcomb_k<<<dim3(256), dim3(256), 0, stream>>>(Wih0, Wout, bout, bih0, bhh0, Wc, bb);
    lstm_persist<<<dim3(256), dim3(256), 0, stream>>>(
        x, Whh0, Wih0, Wih1, Whh1, Wc, bb,
        bih0, bhh0, bih1, bhh1, Wout, bout,
        out, cnt,
        h0h[0], h0h[1], h0l[0], h0l[1], h1h[0], h1h[1], h1l[0], h1l[1],
        c0, c1);
    pred_last<<<dim3(64), dim3(256), 0, stream>>>(h1h[1], h1l[1], Wout, bout, out);
  } else {
    for (int t = 0; t < 432; ++t){
      const int p = t & 1;
      float* gf = (t == 335) ? out : (float*)nullptr;
      if (t < 336)
        l0_fb<true><<<dim3(256), dim3(256), 0, stream>>>(
            x, predh, predl, Wih0, Whh0, bih0, bhh0,
            h0h[p^1], h0l[p^1], h0h[p], h0l[p], c0, t);
      else
        l0_fb<false><<<dim3(256), dim3(256), 0, stream>>>(
            x, predh, predl, Wih0, Whh0, bih0, bhh0,
            h0h[p^1], h0l[p^1], h0h[p], h0l[p], c0, t);
      l1_fb<<<dim3(256), dim3(256), 0, stream>>>(
          Wih1, Whh1, bih1, bhh1, h0h[p], h0l[p],
          h1h[p^1], h1l[p^1], h1h[p], h1l[p], c1, gf);
      if (t >= 336)
        pred_fb<<<dim3(64), dim3(256), 0, stream>>>(
            h1h[p], h1l[p], Wout, bout, predh, predl, out, t - 336);
    }
  }
}

// Round 13
// 27554.089 us; speedup vs baseline: 1.6606x; 1.2479x over previous
//
#include <hip/hip_runtime.h>

typedef unsigned short u16;
typedef __attribute__((ext_vector_type(8))) short short8;
typedef __attribute__((ext_vector_type(4))) float f32x4;

__device__ __forceinline__ float bf2f(u16 v){
  union { unsigned u; float f; } t; t.u = ((unsigned)v) << 16; return t.f;
}
__device__ __forceinline__ u16 f2bf(float f){
  union { float f; unsigned u; } t; t.f = f;
  unsigned u = t.u;
  return (u16)((u + 0x7fffu + ((u >> 16) & 1u)) >> 16);
}
struct HiLo { short hi, lo; };
__device__ __forceinline__ HiLo split1(float v){
  HiLo r;
  u16 h = f2bf(v);
  r.hi = (short)h;
  r.lo = (short)f2bf(v - bf2f(h));
  return r;
}
__device__ __forceinline__ void ldw8s(const float* __restrict__ p, short8& hi, short8& lo){
  #pragma unroll
  for (int j = 0; j < 8; ++j){ HiLo s = split1(p[j]); hi[j] = s.hi; lo[j] = s.lo; }
}

#define MFMA(acc, a, b) acc = __builtin_amdgcn_mfma_f32_16x16x32_bf16(a, b, acc, 0,0,0)
#define SMACC(acc, ah, al, bh, bl) do{ MFMA(acc, ah, bh); MFMA(acc, ah, bl); MFMA(acc, al, bh); }while(0)

// ---- prepass: Wcomb = Wih0 @ Wout (2048x512 f32), bb = bih0+bhh0+Wih0@bout -
__global__ void __launch_bounds__(256) wcomb_k(
    const float* __restrict__ Wih0, const float* __restrict__ Wout,
    const float* __restrict__ bout, const float* __restrict__ bih0,
    const float* __restrict__ bhh0,
    float* __restrict__ Wc, float* __restrict__ bb)
{
  __shared__ float wl[8*64];
  __shared__ float bo[64];
  const int wg = blockIdx.x, tid = threadIdx.x;
  const int r0 = wg*8;
  for (int i = tid; i < 512; i += 256) wl[i] = Wih0[(r0 + (i >> 6))*64 + (i & 63)];
  if (tid < 64) bo[tid] = bout[tid];
  __syncthreads();
  if (tid < 8){
    int n = r0 + tid;
    float a = bih0[n] + bhh0[n];
    #pragma unroll 8
    for (int d = 0; d < 64; ++d) a += wl[tid*64 + d]*bo[d];
    bb[n] = a;
  }
  #pragma unroll
  for (int jj = 0; jj < 2; ++jj){
    int j = tid + jj*256;
    float acc[8] = {0,0,0,0,0,0,0,0};
    for (int d = 0; d < 64; ++d){
      float wv = Wout[d*512 + j];
      #pragma unroll
      for (int r = 0; r < 8; ++r) acc[r] += wl[r*64 + d]*wv;
    }
    #pragma unroll
    for (int r = 0; r < 8; ++r) Wc[(r0 + r)*512 + j] = acc[r];
  }
}

// ---- tree grid barrier: 16 leaf counters -> root -> broadcast flag ---------
// bar[0]: root counter; bar[32]: flag; bar[64 + g*32]: group g counter.
// Each counter on its own 128B line. All relaxed; fences give acq/rel.
// Serial atomic chain: 16 (leaf) + 16 (root) instead of 256 on one line.
__device__ __forceinline__ void gbar(unsigned* bar, unsigned phase){
  __syncthreads();
  if (threadIdx.x == 0){
    __threadfence();    // release: writeback this WG's stores (cross-XCD)
    const unsigned g = (unsigned)blockIdx.x >> 4;
    unsigned old = __hip_atomic_fetch_add(bar + 64 + g*32, 1u,
                     __ATOMIC_RELAXED, __HIP_MEMORY_SCOPE_AGENT);
    if (old == phase*16u - 1u){                 // 16th arrival of this group
      unsigned r = __hip_atomic_fetch_add(bar, 1u,
                     __ATOMIC_RELAXED, __HIP_MEMORY_SCOPE_AGENT);
      if (r == phase*16u - 1u)                  // 16th group this phase
        __hip_atomic_store(bar + 32, phase,
                     __ATOMIC_RELAXED, __HIP_MEMORY_SCOPE_AGENT);
    }
    while (__hip_atomic_load(bar + 32, __ATOMIC_RELAXED, __HIP_MEMORY_SCOPE_AGENT) < phase)
      __builtin_amdgcn_s_sleep(2);
    __threadfence();    // acquire: one invalidate before reading peers' data
  }
  __syncthreads();
}

// ---- LDS weight-slice helpers (XOR-swizzled, G4) ---------------------------
__device__ __forceinline__ short8 lds8(const u16* base, int r, int kelem, int rowbytes){
  int bo = r*rowbytes + (((kelem*2)) ^ ((r & 7) << 4));
  return *(const short8*)((const char*)base + bo);
}
__device__ __forceinline__ void load_slice(
    const float* __restrict__ W, int ldw, int rowshift, int nelem,
    u16* lh, u16* ll, int jq, int tid)
{
  const int rowbytes = ldw*2;
  for (int i = tid; i < nelem; i += 256){
    int r = i >> rowshift, k = i & ((1 << rowshift) - 1);
    int n = ((r >> 2) << 9) + jq*4 + (r & 3);     // gate=(r>>2), col=jq*4+(r&3)
    HiLo s = split1(W[n*ldw + k]);
    int bo = r*rowbytes + (((k*2)) ^ ((r & 7) << 4));
    *(u16*)((char*)lh + bo) = (u16)s.hi;
    *(u16*)((char*)ll + bo) = (u16)s.lo;
  }
}

// ---- persistent kernel: all weights LDS-resident ---------------------------
// WG = (mhalf, jq): 128 batch rows x 4 hidden cols (16 gate rows).
__global__ void __launch_bounds__(256, 1) lstm_persist(
    const float* __restrict__ x,
    const float* __restrict__ Whh0, const float* __restrict__ Wih0,
    const float* __restrict__ Wih1, const float* __restrict__ Whh1,
    const float* __restrict__ Wc,   const float* __restrict__ bb,
    const float* __restrict__ bih0, const float* __restrict__ bhh0,
    const float* __restrict__ bih1, const float* __restrict__ bhh1,
    const float* __restrict__ Wout, const float* __restrict__ bout,
    float* __restrict__ out, unsigned* __restrict__ cnt,
    u16* __restrict__ h0h0, u16* __restrict__ h0h1,
    u16* __restrict__ h0l0, u16* __restrict__ h0l1,
    u16* __restrict__ h1h0, u16* __restrict__ h1h1,
    u16* __restrict__ h1l0, u16* __restrict__ h1l1,
    float* __restrict__ c0, float* __restrict__ c1)
{
  __shared__ u16 w0hh_h[8192], w0hh_l[8192];     // 16x512 bf16 hi/lo, swizzled
  __shared__ u16 w1ih_h[8192], w1ih_l[8192];
  __shared__ u16 w1hh_h[8192], w1hh_l[8192];
  __shared__ u16 wcmb_h[8192], wcmb_l[8192];
  __shared__ u16 w0ih_h[1024], w0ih_l[1024];     // 16x64
  __shared__ float gl[128*17];                   // gate exchange
  __shared__ float pr[128*2];                    // pred partials
  __shared__ float bs0[16], bs1[16], bsd[16];

  const int wg = blockIdx.x, tid = threadIdx.x;
  const int mhalf = wg & 1, jq = wg >> 1;        // 2 x 128 WGs
  const int lane = tid & 63, wv = tid >> 6;
  const int cI = lane & 15;
  const int kc = (lane >> 4) << 3;

  // ---- one-time init: stage + split weight slices into LDS ----
  load_slice(Whh0, 512, 9, 8192, w0hh_h, w0hh_l, jq, tid);
  load_slice(Wih1, 512, 9, 8192, w1ih_h, w1ih_l, jq, tid);
  load_slice(Whh1, 512, 9, 8192, w1hh_h, w1hh_l, jq, tid);
  load_slice(Wc,   512, 9, 8192, wcmb_h, wcmb_l, jq, tid);
  load_slice(Wih0,  64, 6, 1024, w0ih_h, w0ih_l, jq, tid);
  if (tid < 16){
    int n = ((tid >> 2) << 9) + jq*4 + (tid & 3);
    bs0[tid] = bih0[n] + bhh0[n];
    bs1[tid] = bih1[n] + bhh1[n];
    bsd[tid] = bb[n];
  }
  __syncthreads();

  const int ar0 = mhalf*128 + wv*32 + cI;        // M-tile 0 batch row
  const int ar1 = ar0 + 16;                      // M-tile 1
  const int aoff0 = ar0*512 + kc, aoff1 = ar1*512 + kc;

  u16* H0h[2] = { h0h0, h0h1 };  u16* H0l[2] = { h0l0, h0l1 };
  u16* H1h[2] = { h1h0, h1h1 };  u16* H1l[2] = { h1l0, h1l1 };

  const float* xb0 = x + ar0*21504;              // x[b][d][t]
  const float* xb1 = x + ar1*21504;

  unsigned ep = 0;

  for (int t = 0; t < 432; ++t){
    const int p = t & 1;
    const bool enc = (t < 336);

    // =============== phase A: layer 0 ===============
    f32x4 A0 = {0,0,0,0}, A1 = {0,0,0,0};
    if (enc){
      #pragma unroll
      for (int ks = 0; ks < 2; ++ks){            // x segment (K=64)
        int k = kc + ks*32;
        short8 a0h, a0l, a1h, a1l;
        #pragma unroll
        for (int j = 0; j < 8; ++j){
          HiLo s0 = split1(xb0[(k + j)*336 + t]); a0h[j] = s0.hi; a0l[j] = s0.lo;
          HiLo s1 = split1(xb1[(k + j)*336 + t]); a1h[j] = s1.hi; a1l[j] = s1.lo;
        }
        short8 bh = lds8(w0ih_h, cI, k, 128);
        short8 bl = lds8(w0ih_l, cI, k, 128);
        SMACC(A0, a0h, a0l, bh, bl);
        SMACC(A1, a1h, a1l, bh, bl);
      }
    } else if (t > 336){                         // Wcomb segment over h1_{t-1}
      const u16* hH = H1h[p^1]; const u16* hL = H1l[p^1];
      #pragma unroll 4
      for (int ks = 0; ks < 16; ++ks){
        int k = ks*32;
        short8 a0h = *(const short8*)(hH + aoff0 + k);
        short8 a0l = *(const short8*)(hL + aoff0 + k);
        short8 a1h = *(const short8*)(hH + aoff1 + k);
        short8 a1l = *(const short8*)(hL + aoff1 + k);
        short8 bh = lds8(wcmb_h, cI, kc + k, 1024);
        short8 bl = lds8(wcmb_l, cI, kc + k, 1024);
        SMACC(A0, a0h, a0l, bh, bl);
        SMACC(A1, a1h, a1l, bh, bl);
      }
    }
    {                                            // Whh0 segment over h0_{t-1}
      const u16* hH = H0h[p^1]; const u16* hL = H0l[p^1];
      #pragma unroll 4
      for (int ks = 0; ks < 16; ++ks){
        int k = ks*32;
        short8 a0h = *(const short8*)(hH + aoff0 + k);
        short8 a0l = *(const short8*)(hL + aoff0 + k);
        short8 a1h = *(const short8*)(hH + aoff1 + k);
        short8 a1l = *(const short8*)(hL + aoff1 + k);
        short8 bh = lds8(w0hh_h, cI, kc + k, 1024);
        short8 bl = lds8(w0hh_l, cI, kc + k, 1024);
        SMACC(A0, a0h, a0l, bh, bl);
        SMACC(A1, a1h, a1l, bh, bl);
      }
    }
    // decoder pred output l = t-337 from h1_{t-1} (WGs jq<64 own col d=jq)
    if (!enc && t > 336 && jq < 64){
      const int bl_ = tid & 127, q = tid >> 7;
      const int b = mhalf*128 + bl_;
      const u16* hH = H1h[p^1] + b*512 + q*256;
      const u16* hL = H1l[p^1] + b*512 + q*256;
      const float* wr = Wout + jq*512 + q*256;
      float part = 0.f;
      #pragma unroll 4
      for (int k = 0; k < 256; k += 8){
        short8 hv = *(const short8*)(hH + k);
        short8 lv = *(const short8*)(hL + k);
        #pragma unroll
        for (int j = 0; j < 8; ++j)
          part += (bf2f((u16)hv[j]) + bf2f((u16)lv[j])) * wr[k + j];
      }
      pr[bl_*2 + q] = part;
      __syncthreads();
      if (tid < 128){
        float v = pr[tid*2] + pr[tid*2 + 1] + bout[jq];
        out[131072 + ((mhalf*128 + tid)*64 + jq)*96 + (t - 337)] = v;
      }
    }
    // cell update A (h0, c0)
    {
      const float* bias = (enc || t == 336) ? bs0 : bsd;
      __syncthreads();
      const int rb = wv*32 + ((lane >> 4) << 2);
      #pragma unroll
      for (int r = 0; r < 4; ++r){
        gl[(rb + r)*17 + cI]      = A0[r] + bias[cI];
        gl[(rb + 16 + r)*17 + cI] = A1[r] + bias[cI];
      }
      __syncthreads();
      #pragma unroll
      for (int q = 0; q < 2; ++q){
        int e = tid + q*256;
        int m = e >> 2, cloc = e & 3;
        float iv = gl[m*17 + cloc];
        float fv = gl[m*17 + 4 + cloc];
        float gv = gl[m*17 + 8 + cloc];
        float ov = gl[m*17 + 12 + cloc];
        float si = 1.f/(1.f + expf(-iv));
        float sf = 1.f/(1.f + expf(-fv));
        float so = 1.f/(1.f + expf(-ov));
        int gi = (mhalf*128 + m)*512 + jq*4 + cloc;
        float cn = sf*c0[gi] + si*tanhf(gv);
        c0[gi] = cn;
        float h = so*tanhf(cn);
        u16 hh = f2bf(h);
        H0h[p][gi] = hh;
        H0l[p][gi] = f2bf(h - bf2f(hh));
      }
    }
    ++ep; gbar(cnt, ep);

    // =============== phase B: layer 1 ===============
    A0 = (f32x4){0,0,0,0}; A1 = (f32x4){0,0,0,0};
    {
      const u16* hH = H0h[p]; const u16* hL = H0l[p];   // h0_t
      #pragma unroll 4
      for (int ks = 0; ks < 16; ++ks){
        int k = ks*32;
        short8 a0h = *(const short8*)(hH + aoff0 + k);
        short8 a0l = *(const short8*)(hL + aoff0 + k);
        short8 a1h = *(const short8*)(hH + aoff1 + k);
        short8 a1l = *(const short8*)(hL + aoff1 + k);
        short8 bh = lds8(w1ih_h, cI, kc + k, 1024);
        short8 bl = lds8(w1ih_l, cI, kc + k, 1024);
        SMACC(A0, a0h, a0l, bh, bl);
        SMACC(A1, a1h, a1l, bh, bl);
      }
    }
    {
      const u16* hH = H1h[p^1]; const u16* hL = H1l[p^1];  // h1_{t-1}
      #pragma unroll 4
      for (int ks = 0; ks < 16; ++ks){
        int k = ks*32;
        short8 a0h = *(const short8*)(hH + aoff0 + k);
        short8 a0l = *(const short8*)(hL + aoff0 + k);
        short8 a1h = *(const short8*)(hH + aoff1 + k);
        short8 a1l = *(const short8*)(hL + aoff1 + k);
        short8 bh = lds8(w1hh_h, cI, kc + k, 1024);
        short8 bl = lds8(w1hh_l, cI, kc + k, 1024);
        SMACC(A0, a0h, a0l, bh, bl);
        SMACC(A1, a1h, a1l, bh, bl);
      }
    }
    {
      float* gf = (t == 335) ? out : (float*)nullptr;
      __syncthreads();
      const int rb = wv*32 + ((lane >> 4) << 2);
      #pragma unroll
      for (int r = 0; r < 4; ++r){
        gl[(rb + r)*17 + cI]      = A0[r] + bs1[cI];
        gl[(rb + 16 + r)*17 + cI] = A1[r] + bs1[cI];
      }
      __syncthreads();
      #pragma unroll
      for (int q = 0; q < 2; ++q){
        int e = tid + q*256;
        int m = e >> 2, cloc = e & 3;
        float iv = gl[m*17 + cloc];
        float fv = gl[m*17 + 4 + cloc];
        float gv = gl[m*17 + 8 + cloc];
        float ov = gl[m*17 + 12 + cloc];
        float si = 1.f/(1.f + expf(-iv));
        float sf = 1.f/(1.f + expf(-fv));
        float so = 1.f/(1.f + expf(-ov));
        int gi = (mhalf*128 + m)*512 + jq*4 + cloc;
        float cn = sf*c1[gi] + si*tanhf(gv);
        c1[gi] = cn;
        float h = so*tanhf(cn);
        u16 hh = f2bf(h);
        H1h[p][gi] = hh;
        H1l[p][gi] = f2bf(h - bf2f(hh));
        if (gf) gf[gi] = h;
      }
    }
    ++ep; gbar(cnt, ep);
  }
}

// ---- tail: pred for l=95 from h1_431 ---------------------------------------
__global__ void __launch_bounds__(256) pred_last(
    const u16* __restrict__ h1hi, const u16* __restrict__ h1lo,
    const float* __restrict__ Wout, const float* __restrict__ bout,
    float* __restrict__ out)
{
  const int wg = blockIdx.x, tid = threadIdx.x;
  const int bsub = tid >> 6, d = tid & 63;
  const int b = wg*4 + bsub;
  float acc = bout[d];
  const u16* hH = h1hi + b*512;
  const u16* hL = h1lo + b*512;
  const float* wr = Wout + d*512;
  #pragma unroll 8
  for (int k = 0; k < 512; k += 8){
    short8 hv = *(const short8*)(hH + k);
    short8 lv = *(const short8*)(hL + k);
    #pragma unroll
    for (int j = 0; j < 8; ++j)
      acc += (bf2f((u16)hv[j]) + bf2f((u16)lv[j])) * wr[k + j];
  }
  out[131072 + (b*64 + d)*96 + 95] = acc;
}

// ======================= fallback (R9 proven path) ==========================
__device__ __forceinline__ void cell_epilogue_fb(
    float* gl, const float* bs, float* __restrict__ cbuf,
    u16* __restrict__ hhi, u16* __restrict__ hlo,
    float* __restrict__ gfout, int mrow, int jblk,
    const f32x4& a0, const f32x4& a1, int wv, int lane, int tid)
{
  __syncthreads();
  const int rbase = wv*16 + ((lane >> 4) << 2);
  const int cI = lane & 15;
  #pragma unroll
  for (int r = 0; r < 4; ++r){
    gl[(rbase+r)*33 + cI]      = a0[r] + bs[cI];
    gl[(rbase+r)*33 + 16 + cI] = a1[r] + bs[16 + cI];
  }
  __syncthreads();
  #pragma unroll
  for (int q = 0; q < 2; ++q){
    int e = tid + q*256;
    int m = e >> 3, jj = e & 7;
    float iv = gl[m*33 + jj];
    float fv = gl[m*33 + 8 + jj];
    float gv = gl[m*33 + 16 + jj];
    float ov = gl[m*33 + 24 + jj];
    float si = 1.f/(1.f + expf(-iv));
    float sf = 1.f/(1.f + expf(-fv));
    float so = 1.f/(1.f + expf(-ov));
    int gi = (mrow*64 + m)*512 + jblk*8 + jj;
    float cn = sf*cbuf[gi] + si*tanhf(gv);
    cbuf[gi] = cn;
    float h = so*tanhf(cn);
    u16 hh = f2bf(h);
    hhi[gi] = hh;
    hlo[gi] = f2bf(h - bf2f(hh));
    if (gfout) gfout[gi] = h;
  }
}

template<bool ENC>
__global__ void __launch_bounds__(256) l0_fb(
    const float* __restrict__ x,
    const u16* __restrict__ predhi, const u16* __restrict__ predlo,
    const float* __restrict__ Wihf, const float* __restrict__ Whhf,
    const float* __restrict__ bih, const float* __restrict__ bhh,
    const u16* __restrict__ hphi, const u16* __restrict__ hplo,
    u16* __restrict__ hnhi, u16* __restrict__ hnlo,
    float* __restrict__ c0, int t)
{
  __shared__ float gl[64*33];
  __shared__ float bs[32];
  const int wg = blockIdx.x, tid = threadIdx.x;
  const int mrow = wg & 3, jblk = wg >> 2;
  const int lane = tid & 63, wv = tid >> 6;
  if (tid < 32){
    int n = ((tid >> 3) << 9) + jblk*8 + (tid & 7);
    bs[tid] = bih[n] + bhh[n];
  }
  const int ar = mrow*64 + wv*16 + (lane & 15);
  const int kc = (lane >> 4) << 3;
  const int cI = lane & 15;
  const int n0 = ((cI >> 3) << 9) + jblk*8 + (cI & 7);
  const int n1 = n0 + 1024;

  f32x4 acc0 = {0,0,0,0}, acc1 = {0,0,0,0};
  #pragma unroll
  for (int ks = 0; ks < 2; ++ks){
    int k = ks*32 + kc;
    short8 ah, al;
    if (ENC){
      const float* xb = x + ar*21504 + t;
      #pragma unroll
      for (int j = 0; j < 8; ++j){ HiLo s = split1(xb[(k + j)*336]); ah[j] = s.hi; al[j] = s.lo; }
    } else {
      ah = *(const short8*)(predhi + ar*64 + k);
      al = *(const short8*)(predlo + ar*64 + k);
    }
    short8 bh0, bl0, bh1, bl1;
    ldw8s(Wihf + n0*64 + k, bh0, bl0);
    ldw8s(Wihf + n1*64 + k, bh1, bl1);
    SMACC(acc0, ah, al, bh0, bl0);
    SMACC(acc1, ah, al, bh1, bl1);
  }
  const u16* hH = hphi + ar*512 + kc;
  const u16* hL = hplo + ar*512 + kc;
  #pragma unroll 4
  for (int ks = 0; ks < 16; ++ks){
    int k = ks*32;
    short8 ah = *(const short8*)(hH + k);
    short8 al = *(const short8*)(hL + k);
    short8 bh0, bl0, bh1, bl1;
    ldw8s(Whhf + n0*512 + kc + k, bh0, bl0);
    ldw8s(Whhf + n1*512 + kc + k, bh1, bl1);
    SMACC(acc0, ah, al, bh0, bl0);
    SMACC(acc1, ah, al, bh1, bl1);
  }
  cell_epilogue_fb(gl, bs, c0, hnhi, hnlo, nullptr, mrow, jblk, acc0, acc1, wv, lane, tid);
}

__global__ void __launch_bounds__(256) l1_fb(
    const float* __restrict__ Wihf, const float* __restrict__ Whhf,
    const float* __restrict__ bih, const float* __restrict__ bhh,
    const u16* __restrict__ h0hi, const u16* __restrict__ h0lo,
    const u16* __restrict__ h1phi, const u16* __restrict__ h1plo,
    u16* __restrict__ h1nhi, u16* __restrict__ h1nlo,
    float* __restrict__ c1, float* __restrict__ gfout)
{
  __shared__ float gl[64*33];
  __shared__ float bs[32];
  const int wg = blockIdx.x, tid = threadIdx.x;
  const int mrow = wg & 3, jblk = wg >> 2;
  const int lane = tid & 63, wv = tid >> 6;
  if (tid < 32){
    int n = ((tid >> 3) << 9) + jblk*8 + (tid & 7);
    bs[tid] = bih[n] + bhh[n];
  }
  const int ar = mrow*64 + wv*16 + (lane & 15);
  const int kc = (lane >> 4) << 3;
  const int cI = lane & 15;
  const int n0 = ((cI >> 3) << 9) + jblk*8 + (cI & 7);
  const int n1 = n0 + 1024;

  f32x4 acc0 = {0,0,0,0}, acc1 = {0,0,0,0};
  {
    const u16* hH = h0hi + ar*512 + kc;
    const u16* hL = h0lo + ar*512 + kc;
    #pragma unroll 4
    for (int ks = 0; ks < 16; ++ks){
      int k = ks*32;
      short8 ah = *(const short8*)(hH + k);
      short8 al = *(const short8*)(hL + k);
      short8 bh0, bl0, bh1, bl1;
      ldw8s(Wihf + n0*512 + kc + k, bh0, bl0);
      ldw8s(Wihf + n1*512 + kc + k, bh1, bl1);
      SMACC(acc0, ah, al, bh0, bl0);
      SMACC(acc1, ah, al, bh1, bl1);
    }
  }
  {
    const u16* hH = h1phi + ar*512 + kc;
    const u16* hL = h1plo + ar*512 + kc;
    #pragma unroll 4
    for (int ks = 0; ks < 16; ++ks){
      int k = ks*32;
      short8 ah = *(const short8*)(hH + k);
      short8 al = *(const short8*)(hL + k);
      short8 bh0, bl0, bh1, bl1;
      ldw8s(Whhf + n0*512 + kc + k, bh0, bl0);
      ldw8s(Whhf + n1*512 + kc + k, bh1, bl1);
      SMACC(acc0, ah, al, bh0, bl0);
      SMACC(acc1, ah, al, bh1, bl1);
    }
  }
  cell_epilogue_fb(gl, bs, c1, h1nhi, h1nlo, gfout, mrow, jblk, acc0, acc1, wv, lane, tid);
}

__global__ void __launch_bounds__(256) pred_fb(
    const u16* __restrict__ h1hi, const u16* __restrict__ h1lo,
    const float* __restrict__ Wout, const float* __restrict__ bout,
    u16* __restrict__ predhi, u16* __restrict__ predlo,
    float* __restrict__ out, int l)
{
  const int wg = blockIdx.x, tid = threadIdx.x;
  const int bsub = tid >> 6, d = tid & 63;
  const int b = wg*4 + bsub;
  float acc = bout[d];
  const u16* hH = h1hi + b*512;
  const u16* hL = h1lo + b*512;
  const float* wr = Wout + d*512;
  #pragma unroll 8
  for (int k = 0; k < 512; k += 8){
    short8 hv = *(const short8*)(hH + k);
    short8 lv = *(const short8*)(hL + k);
    #pragma unroll
    for (int j = 0; j < 8; ++j)
      acc += (bf2f((u16)hv[j]) + bf2f((u16)lv[j])) * wr[k + j];
  }
  HiLo s = split1(acc);
  predhi[b*64 + d] = (u16)s.hi;
  predlo[b*64 + d] = (u16)s.lo;
  out[131072 + (b*64 + d)*96 + l] = acc;
}

extern "C" void kernel_launch(void* const* d_in, const int* in_sizes, int n_in,
                              void* d_out, int out_size, void* d_ws, size_t ws_size,
                              hipStream_t stream)
{
  const float* x    = (const float*)d_in[0];
  const float* Wih0 = (const float*)d_in[1];
  const float* Whh0 = (const float*)d_in[2];
  const float* bih0 = (const float*)d_in[3];
  const float* bhh0 = (const float*)d_in[4];
  const float* Wih1 = (const float*)d_in[5];
  const float* Whh1 = (const float*)d_in[6];
  const float* bih1 = (const float*)d_in[7];
  const float* bhh1 = (const float*)d_in[8];
  const float* Wout = (const float*)d_in[9];
  const float* bout = (const float*)d_in[10];
  float* out = (float*)d_out;

  // ---- ws layout: state 3.07 MB + bar 4 KB + Wcomb 4 MB + bb 8 KB
  char* ws = (char*)d_ws;
  u16* h0h[2] = { (u16*)(ws + 0),       (u16*)(ws + 262144) };
  u16* h0l[2] = { (u16*)(ws + 524288),  (u16*)(ws + 786432) };
  u16* h1h[2] = { (u16*)(ws + 1048576), (u16*)(ws + 1310720) };
  u16* h1l[2] = { (u16*)(ws + 1572864), (u16*)(ws + 1835008) };
  float* c0   = (float*)(ws + 2097152);
  float* c1   = (float*)(ws + 2621440);
  unsigned* cnt = (unsigned*)(ws + 3145728);      // main path (tree barrier, 2.3KB)
  u16* predh  = (u16*)(ws + 3145728);             // fallback path
  u16* predl  = (u16*)(ws + 3178496);
  float* Wc   = (float*)(ws + 3211264);           // 2048x512 f32
  float* bb   = (float*)(ws + 3211264 + 4194304);
  const size_t NEED = 3211264u + 4194304u + 8192u;
  const bool ps = (ws_size >= NEED);

  (void)hipMemsetAsync(d_ws, 0, 3211264, stream);   // state + barrier/predbf

  if (ps){
    wcomb_k<<<dim3(256), dim3(256), 0, stream>>>(Wih0, Wout, bout, bih0, bhh0, Wc, bb);
    lstm_persist<<<dim3(256), dim3(256), 0, stream>>>(
        x, Whh0, Wih0, Wih1, Whh1, Wc, bb,
        bih0, bhh0, bih1, bhh1, Wout, bout,
        out, cnt,
        h0h[0], h0h[1], h0l[0], h0l[1], h1h[0], h1h[1], h1l[0], h1l[1],
        c0, c1);
    pred_last<<<dim3(64), dim3(256), 0, stream>>>(h1h[1], h1l[1], Wout, bout, out);
  } else {
    for (int t = 0; t < 432; ++t){
      const int p = t & 1;
      float* gf = (t == 335) ? out : (float*)nullptr;
      if (t < 336)
        l0_fb<true><<<dim3(256), dim3(256), 0, stream>>>(
            x, predh, predl, Wih0, Whh0, bih0, bhh0,
            h0h[p^1], h0l[p^1], h0h[p], h0l[p], c0, t);
      else
        l0_fb<false><<<dim3(256), dim3(256), 0, stream>>>(
            x, predh, predl, Wih0, Whh0, bih0, bhh0,
            h0h[p^1], h0l[p^1], h0h[p], h0l[p], c0, t);
      l1_fb<<<dim3(256), dim3(256), 0, stream>>>(
          Wih1, Whh1, bih1, bhh1, h0h[p], h0l[p],
          h1h[p^1], h1l[p^1], h1h[p], h1l[p], c1, gf);
      if (t >= 336)
        pred_fb<<<dim3(64), dim3(256), 0, stream>>>(
            h1h[p], h1l[p], Wout, bout, predh, predl, out, t - 336);
    }
  }
}

// Round 14
// 18210.248 us; speedup vs baseline: 2.5127x; 1.5131x over previous
//
#include <hip/hip_runtime.h>

typedef unsigned short u16;
typedef __attribute__((ext_vector_type(8))) short short8;
typedef __attribute__((ext_vector_type(4))) float f32x4;

#define AXR __ATOMIC_RELAXED, __HIP_MEMORY_SCOPE_AGENT

__device__ __forceinline__ float bf2f(u16 v){
  union { unsigned u; float f; } t; t.u = ((unsigned)v) << 16; return t.f;
}
__device__ __forceinline__ u16 f2bf(float f){
  union { float f; unsigned u; } t; t.f = f;
  unsigned u = t.u;
  return (u16)((u + 0x7fffu + ((u >> 16) & 1u)) >> 16);
}
struct HiLo { short hi, lo; };
__device__ __forceinline__ HiLo split1(float v){
  HiLo r;
  u16 h = f2bf(v);
  r.hi = (short)h;
  r.lo = (short)f2bf(v - bf2f(h));
  return r;
}
__device__ __forceinline__ void ldw8s(const float* __restrict__ p, short8& hi, short8& lo){
  #pragma unroll
  for (int j = 0; j < 8; ++j){ HiLo s = split1(p[j]); hi[j] = s.hi; lo[j] = s.lo; }
}

#define MFMA(acc, a, b) acc = __builtin_amdgcn_mfma_f32_16x16x32_bf16(a, b, acc, 0,0,0)
#define SMACC(acc, ah, al, bh, bl) do{ MFMA(acc, ah, bh); MFMA(acc, ah, bl); MFMA(acc, al, bh); }while(0)

// ---- prepass: Wcomb = Wih0 @ Wout (2048x512 f32), bb = bih0+bhh0+Wih0@bout -
__global__ void __launch_bounds__(256) wcomb_k(
    const float* __restrict__ Wih0, const float* __restrict__ Wout,
    const float* __restrict__ bout, const float* __restrict__ bih0,
    const float* __restrict__ bhh0,
    float* __restrict__ Wc, float* __restrict__ bb)
{
  __shared__ float wl[8*64];
  __shared__ float bo[64];
  const int wg = blockIdx.x, tid = threadIdx.x;
  const int r0 = wg*8;
  for (int i = tid; i < 512; i += 256) wl[i] = Wih0[(r0 + (i >> 6))*64 + (i & 63)];
  if (tid < 64) bo[tid] = bout[tid];
  __syncthreads();
  if (tid < 8){
    int n = r0 + tid;
    float a = bih0[n] + bhh0[n];
    #pragma unroll 8
    for (int d = 0; d < 64; ++d) a += wl[tid*64 + d]*bo[d];
    bb[n] = a;
  }
  #pragma unroll
  for (int jj = 0; jj < 2; ++jj){
    int j = tid + jj*256;
    float acc[8] = {0,0,0,0,0,0,0,0};
    for (int d = 0; d < 64; ++d){
      float wv = Wout[d*512 + j];
      #pragma unroll
      for (int r = 0; r < 8; ++r) acc[r] += wl[r*64 + d]*wv;
    }
    #pragma unroll
    for (int r = 0; r < 8; ++r) Wc[(r0 + r)*512 + j] = acc[r];
  }
}

// ---- init-only tree barrier (R13, threadfence-based) -----------------------
// bar[0]: root; bar[32]: flag; bar[64 + g*32]: leaf g (g = blockIdx>>4).
__device__ __forceinline__ void gbar(unsigned* bar, unsigned phase){
  __syncthreads();
  if (threadIdx.x == 0){
    __threadfence();
    const unsigned g = (unsigned)blockIdx.x >> 4;
    unsigned old = __hip_atomic_fetch_add(bar + 64 + g*32, 1u, AXR);
    if (old == phase*16u - 1u){
      unsigned r = __hip_atomic_fetch_add(bar, 1u, AXR);
      if (r == phase*16u - 1u)
        __hip_atomic_store(bar + 32, phase, AXR);
    }
    while (__hip_atomic_load(bar + 32, AXR) < phase)
      __builtin_amdgcn_s_sleep(2);
    __threadfence();
  }
  __syncthreads();
}

// ---- XCD-leader grid barrier: 1 wbl2 + 1 L2-inv per XCD per phase ----------
// layout (unsigned words): xcdPop: 576+x*32, xcdArr: 832+x*32,
// xcdRel: 1088+x*32, root2: 1344, flag2: 1376. Each on own 128B line.
// Release: WG stores are in its XCD L2 after __syncthreads (vmcnt drain);
// leader (last local arriver) buffer_wbl2's the XCD L2, then bumps root.
// Acquire: leader invalidates L2+L1 then opens xcdRel gate; others wait on
// the gate, then invalidate their own vL1 only.
__device__ __forceinline__ void xbar(unsigned* bar, unsigned phase,
                                     unsigned xcd, unsigned pop, unsigned nx){
  __syncthreads();
  if (threadIdx.x == 0){
    unsigned old = __hip_atomic_fetch_add(bar + 832 + xcd*32, 1u, AXR);
    const bool leader = (old == phase*pop - 1u);
    if (leader){
      asm volatile("buffer_wbl2 sc1\n\ts_waitcnt vmcnt(0)" ::: "memory");
      unsigned r = __hip_atomic_fetch_add(bar + 1344, 1u, AXR);
      if (r == phase*nx - 1u)
        __hip_atomic_store(bar + 1376, phase, AXR);
    }
    while (__hip_atomic_load(bar + 1376, AXR) < phase)
      __builtin_amdgcn_s_sleep(2);
    if (leader){
      asm volatile("buffer_inv sc1\n\ts_waitcnt vmcnt(0)" ::: "memory");
      __hip_atomic_store(bar + 1088 + xcd*32, phase, AXR);
    } else {
      while (__hip_atomic_load(bar + 1088 + xcd*32, AXR) < phase)
        __builtin_amdgcn_s_sleep(1);
      asm volatile("buffer_inv\n\ts_waitcnt vmcnt(0)" ::: "memory");
    }
  }
  __syncthreads();
}

// ---- LDS weight-slice helpers (XOR-swizzled, G4) ---------------------------
__device__ __forceinline__ short8 lds8(const u16* base, int r, int kelem, int rowbytes){
  int bo = r*rowbytes + (((kelem*2)) ^ ((r & 7) << 4));
  return *(const short8*)((const char*)base + bo);
}
__device__ __forceinline__ void load_slice(
    const float* __restrict__ W, int ldw, int rowshift, int nelem,
    u16* lh, u16* ll, int jq, int tid)
{
  const int rowbytes = ldw*2;
  for (int i = tid; i < nelem; i += 256){
    int r = i >> rowshift, k = i & ((1 << rowshift) - 1);
    int n = ((r >> 2) << 9) + jq*4 + (r & 3);     // gate=(r>>2), col=jq*4+(r&3)
    HiLo s = split1(W[n*ldw + k]);
    int bo = r*rowbytes + (((k*2)) ^ ((r & 7) << 4));
    *(u16*)((char*)lh + bo) = (u16)s.hi;
    *(u16*)((char*)ll + bo) = (u16)s.lo;
  }
}

// ---- persistent kernel: all weights LDS-resident ---------------------------
// WG = (mhalf, jq): 128 batch rows x 4 hidden cols (16 gate rows).
__global__ void __launch_bounds__(256, 1) lstm_persist(
    const float* __restrict__ x,
    const float* __restrict__ Whh0, const float* __restrict__ Wih0,
    const float* __restrict__ Wih1, const float* __restrict__ Whh1,
    const float* __restrict__ Wc,   const float* __restrict__ bb,
    const float* __restrict__ bih0, const float* __restrict__ bhh0,
    const float* __restrict__ bih1, const float* __restrict__ bhh1,
    const float* __restrict__ Wout, const float* __restrict__ bout,
    float* __restrict__ out, unsigned* __restrict__ cnt,
    u16* __restrict__ h0h0, u16* __restrict__ h0h1,
    u16* __restrict__ h0l0, u16* __restrict__ h0l1,
    u16* __restrict__ h1h0, u16* __restrict__ h1h1,
    u16* __restrict__ h1l0, u16* __restrict__ h1l1,
    float* __restrict__ c0, float* __restrict__ c1)
{
  __shared__ u16 w0hh_h[8192], w0hh_l[8192];     // 16x512 bf16 hi/lo, swizzled
  __shared__ u16 w1ih_h[8192], w1ih_l[8192];
  __shared__ u16 w1hh_h[8192], w1hh_l[8192];
  __shared__ u16 wcmb_h[8192], wcmb_l[8192];
  __shared__ u16 w0ih_h[1024], w0ih_l[1024];     // 16x64
  __shared__ float gl[128*17];                   // gate exchange
  __shared__ float pr[128*2];                    // pred partials
  __shared__ float bs0[16], bs1[16], bsd[16];
  __shared__ unsigned s_pop, s_nx;

  const int wg = blockIdx.x, tid = threadIdx.x;
  const int mhalf = wg & 1, jq = wg >> 1;        // 2 x 128 WGs
  const int lane = tid & 63, wv = tid >> 6;
  const int cI = lane & 15;
  const int kc = (lane >> 4) << 3;

  // ---- one-time init: stage + split weight slices into LDS ----
  load_slice(Whh0, 512, 9, 8192, w0hh_h, w0hh_l, jq, tid);
  load_slice(Wih1, 512, 9, 8192, w1ih_h, w1ih_l, jq, tid);
  load_slice(Whh1, 512, 9, 8192, w1hh_h, w1hh_l, jq, tid);
  load_slice(Wc,   512, 9, 8192, wcmb_h, wcmb_l, jq, tid);
  load_slice(Wih0,  64, 6, 1024, w0ih_h, w0ih_l, jq, tid);
  if (tid < 16){
    int n = ((tid >> 2) << 9) + jq*4 + (tid & 3);
    bs0[tid] = bih0[n] + bhh0[n];
    bs1[tid] = bih1[n] + bhh1[n];
    bsd[tid] = bb[n];
  }

  // ---- XCD census: pop (WGs on my XCD), nx (active XCDs) ----
  unsigned xcd;
  asm volatile("s_getreg_b32 %0, hwreg(HW_REG_XCC_ID)" : "=s"(xcd));
  xcd &= 7u;
  if (tid == 0)
    __hip_atomic_fetch_add(cnt + 576 + xcd*32, 1u, AXR);
  gbar(cnt, 1);                   // pops final (also covers LDS staging)
  if (tid == 0){
    unsigned nxl = 0;
    for (int i = 0; i < 8; ++i)
      nxl += (__hip_atomic_load(cnt + 576 + i*32, AXR) != 0u) ? 1u : 0u;
    s_pop = __hip_atomic_load(cnt + 576 + xcd*32, AXR);
    s_nx  = nxl;
  }
  __syncthreads();
  const unsigned pop = s_pop, nx = s_nx;

  const int ar0 = mhalf*128 + wv*32 + cI;        // M-tile 0 batch row
  const int ar1 = ar0 + 16;                      // M-tile 1
  const int aoff0 = ar0*512 + kc, aoff1 = ar1*512 + kc;

  u16* H0h[2] = { h0h0, h0h1 };  u16* H0l[2] = { h0l0, h0l1 };
  u16* H1h[2] = { h1h0, h1h1 };  u16* H1l[2] = { h1l0, h1l1 };

  const float* xb0 = x + ar0*21504;              // x[b][d][t]
  const float* xb1 = x + ar1*21504;

  unsigned ep = 0;

  for (int t = 0; t < 432; ++t){
    const int p = t & 1;
    const bool enc = (t < 336);

    // =============== phase A: layer 0 ===============
    f32x4 A0 = {0,0,0,0}, A1 = {0,0,0,0};
    if (enc){
      #pragma unroll
      for (int ks = 0; ks < 2; ++ks){            // x segment (K=64)
        int k = kc + ks*32;
        short8 a0h, a0l, a1h, a1l;
        #pragma unroll
        for (int j = 0; j < 8; ++j){
          HiLo s0 = split1(xb0[(k + j)*336 + t]); a0h[j] = s0.hi; a0l[j] = s0.lo;
          HiLo s1 = split1(xb1[(k + j)*336 + t]); a1h[j] = s1.hi; a1l[j] = s1.lo;
        }
        short8 bh = lds8(w0ih_h, cI, k, 128);
        short8 bl = lds8(w0ih_l, cI, k, 128);
        SMACC(A0, a0h, a0l, bh, bl);
        SMACC(A1, a1h, a1l, bh, bl);
      }
    } else if (t > 336){                         // Wcomb segment over h1_{t-1}
      const u16* hH = H1h[p^1]; const u16* hL = H1l[p^1];
      #pragma unroll 4
      for (int ks = 0; ks < 16; ++ks){
        int k = ks*32;
        short8 a0h = *(const short8*)(hH + aoff0 + k);
        short8 a0l = *(const short8*)(hL + aoff0 + k);
        short8 a1h = *(const short8*)(hH + aoff1 + k);
        short8 a1l = *(const short8*)(hL + aoff1 + k);
        short8 bh = lds8(wcmb_h, cI, kc + k, 1024);
        short8 bl = lds8(wcmb_l, cI, kc + k, 1024);
        SMACC(A0, a0h, a0l, bh, bl);
        SMACC(A1, a1h, a1l, bh, bl);
      }
    }
    {                                            // Whh0 segment over h0_{t-1}
      const u16* hH = H0h[p^1]; const u16* hL = H0l[p^1];
      #pragma unroll 4
      for (int ks = 0; ks < 16; ++ks){
        int k = ks*32;
        short8 a0h = *(const short8*)(hH + aoff0 + k);
        short8 a0l = *(const short8*)(hL + aoff0 + k);
        short8 a1h = *(const short8*)(hH + aoff1 + k);
        short8 a1l = *(const short8*)(hL + aoff1 + k);
        short8 bh = lds8(w0hh_h, cI, kc + k, 1024);
        short8 bl = lds8(w0hh_l, cI, kc + k, 1024);
        SMACC(A0, a0h, a0l, bh, bl);
        SMACC(A1, a1h, a1l, bh, bl);
      }
    }
    // decoder pred output l = t-337 from h1_{t-1} (WGs jq<64 own col d=jq)
    if (!enc && t > 336 && jq < 64){
      const int bl_ = tid & 127, q = tid >> 7;
      const int b = mhalf*128 + bl_;
      const u16* hH = H1h[p^1] + b*512 + q*256;
      const u16* hL = H1l[p^1] + b*512 + q*256;
      const float* wr = Wout + jq*512 + q*256;
      float part = 0.f;
      #pragma unroll 4
      for (int k = 0; k < 256; k += 8){
        short8 hv = *(const short8*)(hH + k);
        short8 lv = *(const short8*)(hL + k);
        #pragma unroll
        for (int j = 0; j < 8; ++j)
          part += (bf2f((u16)hv[j]) + bf2f((u16)lv[j])) * wr[k + j];
      }
      pr[bl_*2 + q] = part;
      __syncthreads();
      if (tid < 128){
        float v = pr[tid*2] + pr[tid*2 + 1] + bout[jq];
        out[131072 + ((mhalf*128 + tid)*64 + jq)*96 + (t - 337)] = v;
      }
    }
    // cell update A (h0, c0)
    {
      const float* bias = (enc || t == 336) ? bs0 : bsd;
      __syncthreads();
      const int rb = wv*32 + ((lane >> 4) << 2);
      #pragma unroll
      for (int r = 0; r < 4; ++r){
        gl[(rb + r)*17 + cI]      = A0[r] + bias[cI];
        gl[(rb + 16 + r)*17 + cI] = A1[r] + bias[cI];
      }
      __syncthreads();
      #pragma unroll
      for (int q = 0; q < 2; ++q){
        int e = tid + q*256;
        int m = e >> 2, cloc = e & 3;
        float iv = gl[m*17 + cloc];
        float fv = gl[m*17 + 4 + cloc];
        float gv = gl[m*17 + 8 + cloc];
        float ov = gl[m*17 + 12 + cloc];
        float si = 1.f/(1.f + expf(-iv));
        float sf = 1.f/(1.f + expf(-fv));
        float so = 1.f/(1.f + expf(-ov));
        int gi = (mhalf*128 + m)*512 + jq*4 + cloc;
        float cn = sf*c0[gi] + si*tanhf(gv);
        c0[gi] = cn;
        float h = so*tanhf(cn);
        u16 hh = f2bf(h);
        H0h[p][gi] = hh;
        H0l[p][gi] = f2bf(h - bf2f(hh));
      }
    }
    ++ep; xbar(cnt, ep, xcd, pop, nx);

    // =============== phase B: layer 1 ===============
    A0 = (f32x4){0,0,0,0}; A1 = (f32x4){0,0,0,0};
    {
      const u16* hH = H0h[p]; const u16* hL = H0l[p];   // h0_t
      #pragma unroll 4
      for (int ks = 0; ks < 16; ++ks){
        int k = ks*32;
        short8 a0h = *(const short8*)(hH + aoff0 + k);
        short8 a0l = *(const short8*)(hL + aoff0 + k);
        short8 a1h = *(const short8*)(hH + aoff1 + k);
        short8 a1l = *(const short8*)(hL + aoff1 + k);
        short8 bh = lds8(w1ih_h, cI, kc + k, 1024);
        short8 bl = lds8(w1ih_l, cI, kc + k, 1024);
        SMACC(A0, a0h, a0l, bh, bl);
        SMACC(A1, a1h, a1l, bh, bl);
      }
    }
    {
      const u16* hH = H1h[p^1]; const u16* hL = H1l[p^1];  // h1_{t-1}
      #pragma unroll 4
      for (int ks = 0; ks < 16; ++ks){
        int k = ks*32;
        short8 a0h = *(const short8*)(hH + aoff0 + k);
        short8 a0l = *(const short8*)(hL + aoff0 + k);
        short8 a1h = *(const short8*)(hH + aoff1 + k);
        short8 a1l = *(const short8*)(hL + aoff1 + k);
        short8 bh = lds8(w1hh_h, cI, kc + k, 1024);
        short8 bl = lds8(w1hh_l, cI, kc + k, 1024);
        SMACC(A0, a0h, a0l, bh, bl);
        SMACC(A1, a1h, a1l, bh, bl);
      }
    }
    {
      float* gf = (t == 335) ? out : (float*)nullptr;
      __syncthreads();
      const int rb = wv*32 + ((lane >> 4) << 2);
      #pragma unroll
      for (int r = 0; r < 4; ++r){
        gl[(rb + r)*17 + cI]      = A0[r] + bs1[cI];
        gl[(rb + 16 + r)*17 + cI] = A1[r] + bs1[cI];
      }
      __syncthreads();
      #pragma unroll
      for (int q = 0; q < 2; ++q){
        int e = tid + q*256;
        int m = e >> 2, cloc = e & 3;
        float iv = gl[m*17 + cloc];
        float fv = gl[m*17 + 4 + cloc];
        float gv = gl[m*17 + 8 + cloc];
        float ov = gl[m*17 + 12 + cloc];
        float si = 1.f/(1.f + expf(-iv));
        float sf = 1.f/(1.f + expf(-fv));
        float so = 1.f/(1.f + expf(-ov));
        int gi = (mhalf*128 + m)*512 + jq*4 + cloc;
        float cn = sf*c1[gi] + si*tanhf(gv);
        c1[gi] = cn;
        float h = so*tanhf(cn);
        u16 hh = f2bf(h);
        H1h[p][gi] = hh;
        H1l[p][gi] = f2bf(h - bf2f(hh));
        if (gf) gf[gi] = h;
      }
    }
    ++ep; xbar(cnt, ep, xcd, pop, nx);
  }
}

// ---- tail: pred for l=95 from h1_431 ---------------------------------------
__global__ void __launch_bounds__(256) pred_last(
    const u16* __restrict__ h1hi, const u16* __restrict__ h1lo,
    const float* __restrict__ Wout, const float* __restrict__ bout,
    float* __restrict__ out)
{
  const int wg = blockIdx.x, tid = threadIdx.x;
  const int bsub = tid >> 6, d = tid & 63;
  const int b = wg*4 + bsub;
  float acc = bout[d];
  const u16* hH = h1hi + b*512;
  const u16* hL = h1lo + b*512;
  const float* wr = Wout + d*512;
  #pragma unroll 8
  for (int k = 0; k < 512; k += 8){
    short8 hv = *(const short8*)(hH + k);
    short8 lv = *(const short8*)(hL + k);
    #pragma unroll
    for (int j = 0; j < 8; ++j)
      acc += (bf2f((u16)hv[j]) + bf2f((u16)lv[j])) * wr[k + j];
  }
  out[131072 + (b*64 + d)*96 + 95] = acc;
}

// ======================= fallback (R9 proven path) ==========================
__device__ __forceinline__ void cell_epilogue_fb(
    float* gl, const float* bs, float* __restrict__ cbuf,
    u16* __restrict__ hhi, u16* __restrict__ hlo,
    float* __restrict__ gfout, int mrow, int jblk,
    const f32x4& a0, const f32x4& a1, int wv, int lane, int tid)
{
  __syncthreads();
  const int rbase = wv*16 + ((lane >> 4) << 2);
  const int cI = lane & 15;
  #pragma unroll
  for (int r = 0; r < 4; ++r){
    gl[(rbase+r)*33 + cI]      = a0[r] + bs[cI];
    gl[(rbase+r)*33 + 16 + cI] = a1[r] + bs[16 + cI];
  }
  __syncthreads();
  #pragma unroll
  for (int q = 0; q < 2; ++q){
    int e = tid + q*256;
    int m = e >> 3, jj = e & 7;
    float iv = gl[m*33 + jj];
    float fv = gl[m*33 + 8 + jj];
    float gv = gl[m*33 + 16 + jj];
    float ov = gl[m*33 + 24 + jj];
    float si = 1.f/(1.f + expf(-iv));
    float sf = 1.f/(1.f + expf(-fv));
    float so = 1.f/(1.f + expf(-ov));
    int gi = (mrow*64 + m)*512 + jblk*8 + jj;
    float cn = sf*cbuf[gi] + si*tanhf(gv);
    cbuf[gi] = cn;
    float h = so*tanhf(cn);
    u16 hh = f2bf(h);
    hhi[gi] = hh;
    hlo[gi] = f2bf(h - bf2f(hh));
    if (gfout) gfout[gi] = h;
  }
}

template<bool ENC>
__global__ void __launch_bounds__(256) l0_fb(
    const float* __restrict__ x,
    const u16* __restrict__ predhi, const u16* __restrict__ predlo,
    const float* __restrict__ Wihf, const float* __restrict__ Whhf,
    const float* __restrict__ bih, const float* __restrict__ bhh,
    const u16* __restrict__ hphi, const u16* __restrict__ hplo,
    u16* __restrict__ hnhi, u16* __restrict__ hnlo,
    float* __restrict__ c0, int t)
{
  __shared__ float gl[64*33];
  __shared__ float bs[32];
  const int wg = blockIdx.x, tid = threadIdx.x;
  const int mrow = wg & 3, jblk = wg >> 2;
  const int lane = tid & 63, wv = tid >> 6;
  if (tid < 32){
    int n = ((tid >> 3) << 9) + jblk*8 + (tid & 7);
    bs[tid] = bih[n] + bhh[n];
  }
  const int ar = mrow*64 + wv*16 + (lane & 15);
  const int kc = (lane >> 4) << 3;
  const int cI = lane & 15;
  const int n0 = ((cI >> 3) << 9) + jblk*8 + (cI & 7);
  const int n1 = n0 + 1024;

  f32x4 acc0 = {0,0,0,0}, acc1 = {0,0,0,0};
  #pragma unroll
  for (int ks = 0; ks < 2; ++ks){
    int k = ks*32 + kc;
    short8 ah, al;
    if (ENC){
      const float* xb = x + ar*21504 + t;
      #pragma unroll
      for (int j = 0; j < 8; ++j){ HiLo s = split1(xb[(k + j)*336]); ah[j] = s.hi; al[j] = s.lo; }
    } else {
      ah = *(const short8*)(predhi + ar*64 + k);
      al = *(const short8*)(predlo + ar*64 + k);
    }
    short8 bh0, bl0, bh1, bl1;
    ldw8s(Wihf + n0*64 + k, bh0, bl0);
    ldw8s(Wihf + n1*64 + k, bh1, bl1);
    SMACC(acc0, ah, al, bh0, bl0);
    SMACC(acc1, ah, al, bh1, bl1);
  }
  const u16* hH = hphi + ar*512 + kc;
  const u16* hL = hplo + ar*512 + kc;
  #pragma unroll 4
  for (int ks = 0; ks < 16; ++ks){
    int k = ks*32;
    short8 ah = *(const short8*)(hH + k);
    short8 al = *(const short8*)(hL + k);
    short8 bh0, bl0, bh1, bl1;
    ldw8s(Whhf + n0*512 + kc + k, bh0, bl0);
    ldw8s(Whhf + n1*512 + kc + k, bh1, bl1);
    SMACC(acc0, ah, al, bh0, bl0);
    SMACC(acc1, ah, al, bh1, bl1);
  }
  cell_epilogue_fb(gl, bs, c0, hnhi, hnlo, nullptr, mrow, jblk, acc0, acc1, wv, lane, tid);
}

__global__ void __launch_bounds__(256) l1_fb(
    const float* __restrict__ Wihf, const float* __restrict__ Whhf,
    const float* __restrict__ bih, const float* __restrict__ bhh,
    const u16* __restrict__ h0hi, const u16* __restrict__ h0lo,
    const u16* __restrict__ h1phi, const u16* __restrict__ h1plo,
    u16* __restrict__ h1nhi, u16* __restrict__ h1nlo,
    float* __restrict__ c1, float* __restrict__ gfout)
{
  __shared__ float gl[64*33];
  __shared__ float bs[32];
  const int wg = blockIdx.x, tid = threadIdx.x;
  const int mrow = wg & 3, jblk = wg >> 2;
  const int lane = tid & 63, wv = tid >> 6;
  if (tid < 32){
    int n = ((tid >> 3) << 9) + jblk*8 + (tid & 7);
    bs[tid] = bih[n] + bhh[n];
  }
  const int ar = mrow*64 + wv*16 + (lane & 15);
  const int kc = (lane >> 4) << 3;
  const int cI = lane & 15;
  const int n0 = ((cI >> 3) << 9) + jblk*8 + (cI & 7);
  const int n1 = n0 + 1024;

  f32x4 acc0 = {0,0,0,0}, acc1 = {0,0,0,0};
  {
    const u16* hH = h0hi + ar*512 + kc;
    const u16* hL = h0lo + ar*512 + kc;
    #pragma unroll 4
    for (int ks = 0; ks < 16; ++ks){
      int k = ks*32;
      short8 ah = *(const short8*)(hH + k);
      short8 al = *(const short8*)(hL + k);
      short8 bh0, bl0, bh1, bl1;
      ldw8s(Wihf + n0*512 + kc + k, bh0, bl0);
      ldw8s(Wihf + n1*512 + kc + k, bh1, bl1);
      SMACC(acc0, ah, al, bh0, bl0);
      SMACC(acc1, ah, al, bh1, bl1);
    }
  }
  {
    const u16* hH = h1phi + ar*512 + kc;
    const u16* hL = h1plo + ar*512 + kc;
    #pragma unroll 4
    for (int ks = 0; ks < 16; ++ks){
      int k = ks*32;
      short8 ah = *(const short8*)(hH + k);
      short8 al = *(const short8*)(hL + k);
      short8 bh0, bl0, bh1, bl1;
      ldw8s(Whhf + n0*512 + kc + k, bh0, bl0);
      ldw8s(Whhf + n1*512 + kc + k, bh1, bl1);
      SMACC(acc0, ah, al, bh0, bl0);
      SMACC(acc1, ah, al, bh1, bl1);
    }
  }
  cell_epilogue_fb(gl, bs, c1, h1nhi, h1nlo, gfout, mrow, jblk, acc0, acc1, wv, lane, tid);
}

__global__ void __launch_bounds__(256) pred_fb(
    const u16* __restrict__ h1hi, const u16* __restrict__ h1lo,
    const float* __restrict__ Wout, const float* __restrict__ bout,
    u16* __restrict__ predhi, u16* __restrict__ predlo,
    float* __restrict__ out, int l)
{
  const int wg = blockIdx.x, tid = threadIdx.x;
  const int bsub = tid >> 6, d = tid & 63;
  const int b = wg*4 + bsub;
  float acc = bout[d];
  const u16* hH = h1hi + b*512;
  const u16* hL = h1lo + b*512;
  const float* wr = Wout + d*512;
  #pragma unroll 8
  for (int k = 0; k < 512; k += 8){
    short8 hv = *(const short8*)(hH + k);
    short8 lv = *(const short8*)(hL + k);
    #pragma unroll
    for (int j = 0; j < 8; ++j)
      acc += (bf2f((u16)hv[j]) + bf2f((u16)lv[j])) * wr[k + j];
  }
  HiLo s = split1(acc);
  predhi[b*64 + d] = (u16)s.hi;
  predlo[b*64 + d] = (u16)s.lo;
  out[131072 + (b*64 + d)*96 + l] = acc;
}

extern "C" void kernel_launch(void* const* d_in, const int* in_sizes, int n_in,
                              void* d_out, int out_size, void* d_ws, size_t ws_size,
                              hipStream_t stream)
{
  const float* x    = (const float*)d_in[0];
  const float* Wih0 = (const float*)d_in[1];
  const float* Whh0 = (const float*)d_in[2];
  const float* bih0 = (const float*)d_in[3];
  const float* bhh0 = (const float*)d_in[4];
  const float* Wih1 = (const float*)d_in[5];
  const float* Whh1 = (const float*)d_in[6];
  const float* bih1 = (const float*)d_in[7];
  const float* bhh1 = (const float*)d_in[8];
  const float* Wout = (const float*)d_in[9];
  const float* bout = (const float*)d_in[10];
  float* out = (float*)d_out;

  // ---- ws layout: state 3.07 MB + bar 64 KB + Wcomb 4 MB + bb 8 KB
  char* ws = (char*)d_ws;
  u16* h0h[2] = { (u16*)(ws + 0),       (u16*)(ws + 262144) };
  u16* h0l[2] = { (u16*)(ws + 524288),  (u16*)(ws + 786432) };
  u16* h1h[2] = { (u16*)(ws + 1048576), (u16*)(ws + 1310720) };
  u16* h1l[2] = { (u16*)(ws + 1572864), (u16*)(ws + 1835008) };
  float* c0   = (float*)(ws + 2097152);
  float* c1   = (float*)(ws + 2621440);
  unsigned* cnt = (unsigned*)(ws + 3145728);      // main path barrier area
  u16* predh  = (u16*)(ws + 3145728);             // fallback path
  u16* predl  = (u16*)(ws + 3178496);
  float* Wc   = (float*)(ws + 3211264);           // 2048x512 f32
  float* bb   = (float*)(ws + 3211264 + 4194304);
  const size_t NEED = 3211264u + 4194304u + 8192u;
  const bool ps = (ws_size >= NEED);

  (void)hipMemsetAsync(d_ws, 0, 3211264, stream);   // state + barrier/predbf

  if (ps){
    wcomb_k<<<dim3(256), dim3(256), 0, stream>>>(Wih0, Wout, bout, bih0, bhh0, Wc, bb);
    lstm_persist<<<dim3(256), dim3(256), 0, stream>>>(
        x, Whh0, Wih0, Wih1, Whh1, Wc, bb,
        bih0, bhh0, bih1, bhh1, Wout, bout,
        out, cnt,
        h0h[0], h0h[1], h0l[0], h0l[1], h1h[0], h1h[1], h1l[0], h1l[1],
        c0, c1);
    pred_last<<<dim3(64), dim3(256), 0, stream>>>(h1h[1], h1l[1], Wout, bout, out);
  } else {
    for (int t = 0; t < 432; ++t){
      const int p = t & 1;
      float* gf = (t == 335) ? out : (float*)nullptr;
      if (t < 336)
        l0_fb<true><<<dim3(256), dim3(256), 0, stream>>>(
            x, predh, predl, Wih0, Whh0, bih0, bhh0,
            h0h[p^1], h0l[p^1], h0h[p], h0l[p], c0, t);
      else
        l0_fb<false><<<dim3(256), dim3(256), 0, stream>>>(
            x, predh, predl, Wih0, Whh0, bih0, bhh0,
            h0h[p^1], h0l[p^1], h0h[p], h0l[p], c0, t);
      l1_fb<<<dim3(256), dim3(256), 0, stream>>>(
          Wih1, Whh1, bih1, bhh1, h0h[p], h0l[p],
          h1h[p^1], h1l[p^1], h1h[p], h1l[p], c1, gf);
      if (t >= 336)
        pred_fb<<<dim3(64), dim3(256), 0, stream>>>(
            h1h[p], h1l[p], Wout, bout, predh, predl, out, t - 336);
    }
  }
}